// Round 7
// baseline (292.875 us; speedup 1.0000x reference)
//
#include <hip/hip_runtime.h>

#define BB 2
#define CIN 64
#define FD 257
#define TD 500
#define FT (FD*TD)      // 128500
#define EPS 1e-5f
#define NEGINF (-3.0e38f)
#define FDP 260         // fqT padded row length (halves, 8B-aligned rows)
#define FDP4 260        // foT padded row length (floats, 16B-aligned rows)
#define FQT_PLANE (TD*FDP)   // 130000 halves per (b,channel) plane
#define LOG2E 1.44269504088896f
#define EXP2F(x) __builtin_amdgcn_exp2f(x)

typedef _Float16 half_t;
typedef half_t half2_t __attribute__((ext_vector_type(2)));
typedef half_t half4 __attribute__((ext_vector_type(4)));
typedef float  f32x4 __attribute__((ext_vector_type(4)));

// ---------------------------------------------------------------------------
// Stage 1 (MFMA): out[80, FT] = W[80,64] . x[64, FT], fused BN fold + PReLU.
// Round-6 lesson: scalar dword x-loads (64B granules scattered over 64
// streams) cap DRAM efficiency at ~27%. This round: stage the x tile
// [64ch][128pos] through LDS with float4 global loads (1KB contiguous per
// wave instruction, 8 loads/thread instead of 32). B-fragments gathered
// from LDS (bank-conflict-free pattern). Xs unions with the Ob store slab.
// ---------------------------------------------------------------------------
__global__ __launch_bounds__(256) void stage1_kernel(
    const float* __restrict__ x,
    const float* __restrict__ fw, const float* __restrict__ fb_,
    const float* __restrict__ fg, const float* __restrict__ fbe,
    const float* __restrict__ fm, const float* __restrict__ fv_,
    const float* __restrict__ fa,
    const float* __restrict__ tw, const float* __restrict__ tb_,
    const float* __restrict__ tg, const float* __restrict__ tbe,
    const float* __restrict__ tm, const float* __restrict__ tv_,
    const float* __restrict__ ta,
    half_t* __restrict__ fq, half_t* __restrict__ tq)
{
    __shared__ half_t Wh[80][68];     // folded weights, f16
    __shared__ float  Bl[80];         // folded bias
    __shared__ half_t Slab[10240];    // union: Xs[64][132] (8448) | Ob[4][32][80] (10240)
    const int tid = threadIdx.x;
    for (int idx = tid; idx < 80*64; idx += 256) {
        const int o = idx >> 6, i = idx & 63;
        float sc, wv;
        if (o < 48) { sc = fg[o]*rsqrtf(fv_[o]+EPS); wv = fw[o*64+i]; }
        else { const int o2 = o-48; sc = tg[o2]*rsqrtf(tv_[o2]+EPS); wv = tw[o2*64+i]; }
        Wh[o][i] = (half_t)(wv*sc);
    }
    if (tid < 80) {
        const int o = tid;
        if (o < 48) Bl[o] = (fb_[o]-fm[o])*(fg[o]*rsqrtf(fv_[o]+EPS)) + fbe[o];
        else { const int o2 = o-48; Bl[o] = (tb_[o2]-tm[o2])*(tg[o2]*rsqrtf(tv_[o2]+EPS)) + tbe[o2]; }
    }
    __syncthreads();
    const float af = fa[0], at = ta[0];
    const int w = tid >> 6, lane = tid & 63;
    const int lmod = lane & 15, ldiv = lane >> 4;
    const int b  = blockIdx.x / 1004;
    const int nb = blockIdx.x % 1004;
    const long n0 = (long)nb*128;

    // A fragments (from Wh, which stays live) + bias
    half4 a[5][4];
    #pragma unroll
    for (int ot = 0; ot < 5; ++ot)
        #pragma unroll
        for (int ks = 0; ks < 4; ++ks)
            a[ot][ks] = *(const half4*)&Wh[16*ot + lmod][16*ks + 4*ldiv];
    f32x4 bias[5];
    #pragma unroll
    for (int ot = 0; ot < 5; ++ot)
        #pragma unroll
        for (int r = 0; r < 4; ++r)
            bias[ot][r] = Bl[16*ot + 4*ldiv + r];

    // Stage x tile [64 ch][128 pos] -> Xs (f16), float4 streaming loads.
    const float* xplane = x + (long)b*CIN*FT;
    {
        const int chb = tid >> 5;          // 0..7
        const int pq  = (tid & 31) * 4;    // 0,4,...,124
        const long p4 = n0 + pq;
        #pragma unroll
        for (int pass = 0; pass < 8; ++pass) {
            const int ch = 8*pass + chb;
            half4 hv = {(half_t)0.f,(half_t)0.f,(half_t)0.f,(half_t)0.f};
            if (p4 < FT) {   // FT%4==0: float4 chunks all-or-nothing valid
                const float4 fv = *(const float4*)(xplane + (long)ch*FT + p4);
                hv[0] = (half_t)fv.x; hv[1] = (half_t)fv.y;
                hv[2] = (half_t)fv.z; hv[3] = (half_t)fv.w;
            }
            *(half4*)&Slab[ch*132 + pq] = hv;
        }
    }
    __syncthreads();
    // Gather B fragments from Xs: bfr[pt][ks][e] = Xs[16ks+4ldiv+e][32w+16pt+lmod]
    half4 bfr[2][4];
    #pragma unroll
    for (int pt = 0; pt < 2; ++pt) {
        const int p = 32*w + 16*pt + lmod;
        #pragma unroll
        for (int ks = 0; ks < 4; ++ks)
            #pragma unroll
            for (int e = 0; e < 4; ++e)
                bfr[pt][ks][e] = Slab[(16*ks + 4*ldiv + e)*132 + p];
    }
    __syncthreads();   // Xs dead; Ob overlays the same slab

    #pragma unroll
    for (int pt = 0; pt < 2; ++pt) {
        const int pl = 16*pt + lmod;
        const int msk = ((pl >> 2) & 3) << 2;    // bits 2-3: stays in 16-group
        #pragma unroll
        for (int ot = 0; ot < 5; ++ot) {
            f32x4 acc = bias[ot];
            #pragma unroll
            for (int ks = 0; ks < 4; ++ks)
                acc = __builtin_amdgcn_mfma_f32_16x16x16f16(a[ot][ks], bfr[pt][ks], acc, 0, 0, 0);
            const float alpha = (ot < 3) ? af : at;
            half4 hv;
            #pragma unroll
            for (int r = 0; r < 4; ++r) {
                float v = acc[r];
                v = v >= 0.f ? v : alpha*v;
                hv[r] = (half_t)v;
            }
            // element o=16ot+4ldiv+r lands at col o^msk (msk has no bits 0-1)
            *(half4*)&Slab[w*2560 + pl*80 + ((16*ot + 4*ldiv) ^ msk)] = hv;
        }
    }
    // Store phase: wave-local (same-wave LDS ordering; no extra barrier).
    const int pr = lane & 7, og0 = lane >> 3;
    const long pbase = n0 + 32*w + 4*pr;
    if (pbase < FT) {    // FT%4==0: half4 chunks are all-or-nothing valid
        const int msk = (pr & 3) << 2;           // row 4*pr+e -> (p>>2)&3 == pr&3
        #pragma unroll
        for (int i = 0; i < 10; ++i) {
            const int o = og0 + 8*i;
            half4 hv;
            #pragma unroll
            for (int e = 0; e < 4; ++e) hv[e] = Slab[w*2560 + (4*pr + e)*80 + (o ^ msk)];
            half_t* dst = (o < 48) ? (fq + ((long)b*48 + o)*FT + pbase)
                                   : (tq + ((long)b*32 + (o-48))*FT + pbase);
            *(half4*)dst = hv;
        }
    }
}

// ---------------------------------------------------------------------------
// Transpose (f16->f16): src[plane][R][C] -> dst[plane][C][RP], pad r in
// [R,RP) zeroed. 64x64 tile; half4 (8B/lane) global access on BOTH sides.
// ---------------------------------------------------------------------------
__global__ __launch_bounds__(256) void transpose_h2h_kernel(
    const half_t* __restrict__ src, half_t* __restrict__ dst,
    int R, int C, int RP)
{
    __shared__ half_t tile[64][68];
    const int plane = blockIdx.x;
    const int rb = blockIdx.y*64, cb = blockIdx.z*64;
    const half_t* s = src + (long)plane*R*C;
    half_t* d = dst + (long)plane*C*RP;
    const int q4 = (threadIdx.x & 15)*4;   // 0..60
    const int wl = threadIdx.x >> 4;       // 0..15
    #pragma unroll
    for (int p = 0; p < 4; ++p) {
        const int r = rb + wl + 16*p;
        const int c = cb + q4;
        half4 v = {(half_t)0.f,(half_t)0.f,(half_t)0.f,(half_t)0.f};
        if (r < R) {
            const half_t* srow = s + (long)r*C;
            if (c + 3 < C) v = *(const half4*)(srow + c);
            else {
                #pragma unroll
                for (int e = 0; e < 4; ++e) if (c+e < C) v[e] = srow[c+e];
            }
        }
        *(half4*)&tile[wl + 16*p][q4] = v;
    }
    __syncthreads();
    #pragma unroll
    for (int p = 0; p < 4; ++p) {
        const int c = cb + wl + 16*p;
        if (c >= C) continue;
        const int r0 = rb + q4;
        half4 o;
        #pragma unroll
        for (int e = 0; e < 4; ++e) o[e] = tile[q4 + e][wl + 16*p];
        half_t* drow = d + (long)c*RP;
        if (r0 + 3 < RP) *(half4*)(drow + r0) = o;
        else {
            #pragma unroll
            for (int e = 0; e < 4; ++e) if (r0+e < RP) drow[r0+e] = o[e];
        }
    }
}

// f32 -> f16 variant (for foT -> fo). CS = src row stride (floats, 16B-aligned).
__global__ __launch_bounds__(256) void transpose_f2h_kernel(
    const float* __restrict__ src, half_t* __restrict__ dst,
    int R, int C, int CS, int RP)
{
    __shared__ half_t tile[64][68];
    const int plane = blockIdx.x;
    const int rb = blockIdx.y*64, cb = blockIdx.z*64;
    const float* s = src + (long)plane*R*CS;
    half_t* d = dst + (long)plane*C*RP;
    const int q4 = (threadIdx.x & 15)*4;
    const int wl = threadIdx.x >> 4;
    #pragma unroll
    for (int p = 0; p < 4; ++p) {
        const int r = rb + wl + 16*p;
        const int c = cb + q4;
        half4 v = {(half_t)0.f,(half_t)0.f,(half_t)0.f,(half_t)0.f};
        if (r < R) {
            const float* srow = s + (long)r*CS;
            if (c + 3 < C) {
                const float4 fv = *(const float4*)(srow + c);
                v[0] = (half_t)fv.x; v[1] = (half_t)fv.y;
                v[2] = (half_t)fv.z; v[3] = (half_t)fv.w;
            } else {
                #pragma unroll
                for (int e = 0; e < 4; ++e) if (c+e < C) v[e] = (half_t)srow[c+e];
            }
        }
        *(half4*)&tile[wl + 16*p][q4] = v;
    }
    __syncthreads();
    #pragma unroll
    for (int p = 0; p < 4; ++p) {
        const int c = cb + wl + 16*p;
        if (c >= C) continue;
        const int r0 = rb + q4;
        half4 o;
        #pragma unroll
        for (int e = 0; e < 4; ++e) o[e] = tile[q4 + e][wl + 16*p];
        half_t* drow = d + (long)c*RP;
        if (r0 + 3 < RP) *(half4*)(drow + r0) = o;
        else {
            #pragma unroll
            for (int e = 0; e < 4; ++e) if (r0+e < RP) drow[r0+e] = o[e];
        }
    }
}

// ---------------------------------------------------------------------------
// Stage 2: frequency attention, MFMA flash-style. One block per (b,t),
// 512 threads (8 waves). Paired K-tiles per softmax update; exp2 with
// log2e folded into Q scale.
// ---------------------------------------------------------------------------
__global__ __launch_bounds__(512) void fattn_kernel(
    const half_t* __restrict__ fqT, float* __restrict__ foT)
{
    __shared__ half_t KT[272*20];   // [y][c]
    __shared__ half_t QT[272*20];   // [f][c], pre-scaled by 0.25*log2e
    __shared__ half_t Vs[16*280];   // [c][y]
    const int tid = threadIdx.x;
    const int b = blockIdx.x / TD, t = blockIdx.x % TD;
    const half_t* base = fqT + (long)b*48*FQT_PLANE + (long)t*FDP;
    const half_t qsc = (half_t)(0.25f*LOG2E);
    for (int s = tid; s < 48*68; s += 512) {
        const int c3 = s / 68, j = s - c3*68;
        const int f0 = 4*j;
        half4 v = {(half_t)0.f,(half_t)0.f,(half_t)0.f,(half_t)0.f};
        if (f0 < FDP) v = *(const half4*)(base + (long)c3*FQT_PLANE + f0);
        const int c = c3 / 3, wh = c3 - 3*c;   // q=3c, k=3c+1, v=3c+2
        if (wh == 0) {
            #pragma unroll
            for (int e = 0; e < 4; ++e) QT[(f0+e)*20 + c] = v[e]*qsc;
        } else if (wh == 1) {
            #pragma unroll
            for (int e = 0; e < 4; ++e) KT[(f0+e)*20 + c] = v[e];
        } else {
            *(half4*)&Vs[c*280 + f0] = v;
        }
    }
    __syncthreads();
    const int w = tid >> 6, lane = tid & 63;
    const int lmod = lane & 15, ldiv = lane >> 4;
    for (int ft = w; ft < 17; ft += 8) {    // w=0: {0,8,16}; others {w, w+8}
        const int f0 = 16*ft;
        const half4 qb = *(const half4*)&QT[(f0+lmod)*20 + 4*ldiv];
        f32x4 o = {0.f,0.f,0.f,0.f};
        float m = NEGINF, l = 0.f;
        // 8 pairs of full tiles: y = 0..255, all < FD
        for (int yt = 0; yt < 16; yt += 2) {
            const int y0 = 16*yt;
            const half4 ka0 = *(const half4*)&KT[(y0   +lmod)*20 + 4*ldiv];
            const half4 ka1 = *(const half4*)&KT[(y0+16+lmod)*20 + 4*ldiv];
            f32x4 s0 = __builtin_amdgcn_mfma_f32_16x16x16f16(
                ka0, qb, (f32x4){0.f,0.f,0.f,0.f}, 0, 0, 0);
            f32x4 s1 = __builtin_amdgcn_mfma_f32_16x16x16f16(
                ka1, qb, (f32x4){0.f,0.f,0.f,0.f}, 0, 0, 0);
            float mt = fmaxf(fmaxf(fmaxf(s0[0],s0[1]), fmaxf(s0[2],s0[3])),
                             fmaxf(fmaxf(s1[0],s1[1]), fmaxf(s1[2],s1[3])));
            mt = fmaxf(mt, __shfl_xor(mt, 16, 64));
            mt = fmaxf(mt, __shfl_xor(mt, 32, 64));
            const float mn = fmaxf(m, mt);
            const float alpha = EXP2F(m - mn);
            half4 pb0, pb1; float ps = 0.f;
            #pragma unroll
            for (int r = 0; r < 4; ++r) {
                const float p0 = EXP2F(s0[r] - mn);
                const float p1 = EXP2F(s1[r] - mn);
                pb0[r] = (half_t)p0; pb1[r] = (half_t)p1;
                ps += p0 + p1;
            }
            ps += __shfl_xor(ps, 16, 64);
            ps += __shfl_xor(ps, 32, 64);
            l = l*alpha + ps;  m = mn;
            o[0] *= alpha; o[1] *= alpha; o[2] *= alpha; o[3] *= alpha;
            const half4 va0 = *(const half4*)&Vs[lmod*280 + y0      + 4*ldiv];
            const half4 va1 = *(const half4*)&Vs[lmod*280 + y0 + 16 + 4*ldiv];
            o = __builtin_amdgcn_mfma_f32_16x16x16f16(va0, pb0, o, 0, 0, 0);
            o = __builtin_amdgcn_mfma_f32_16x16x16f16(va1, pb1, o, 0, 0, 0);
        }
        {   // tail tile yt=16: y = 256..271, mask y >= FD
            const int y0 = 256;
            const half4 ka = *(const half4*)&KT[(y0+lmod)*20 + 4*ldiv];
            f32x4 s = __builtin_amdgcn_mfma_f32_16x16x16f16(
                ka, qb, (f32x4){0.f,0.f,0.f,0.f}, 0, 0, 0);
            #pragma unroll
            for (int r = 0; r < 4; ++r)
                if (y0 + 4*ldiv + r >= FD) s[r] = NEGINF;
            float mt = fmaxf(fmaxf(s[0],s[1]), fmaxf(s[2],s[3]));
            mt = fmaxf(mt, __shfl_xor(mt, 16, 64));
            mt = fmaxf(mt, __shfl_xor(mt, 32, 64));
            const float mn = fmaxf(m, mt);
            const float alpha = EXP2F(m - mn);
            half4 pb; float ps = 0.f;
            #pragma unroll
            for (int r = 0; r < 4; ++r) {
                const float p = EXP2F(s[r] - mn);
                pb[r] = (half_t)p; ps += p;
            }
            ps += __shfl_xor(ps, 16, 64);
            ps += __shfl_xor(ps, 32, 64);
            l = l*alpha + ps;  m = mn;
            o[0] *= alpha; o[1] *= alpha; o[2] *= alpha; o[3] *= alpha;
            const half4 va = *(const half4*)&Vs[lmod*280 + y0 + 4*ldiv];
            o = __builtin_amdgcn_mfma_f32_16x16x16f16(va, pb, o, 0, 0, 0);
        }
        const float inv = 1.f/l;
        const int f = f0 + lmod;
        if (f < FD) {
            #pragma unroll
            for (int r = 0; r < 4; ++r) {
                const int c = 4*ldiv + r;
                foT[((long)(b*16 + c)*TD + t)*FDP4 + f] = o[r]*inv;
            }
        }
    }
}

// ---------------------------------------------------------------------------
// Stage 3: causal time attention. One block per (b,f), 512 threads (8 waves).
// half4 vectorized loads; paired K-tiles; exp2 with log2e folded into Q scale.
// ---------------------------------------------------------------------------
__global__ __launch_bounds__(512) void tattn_kernel(
    const half_t* __restrict__ tq, const half_t* __restrict__ fo,
    float* __restrict__ tout)
{
    extern __shared__ half_t lds[];
    half_t* KT  = lds;              // [512 y][20]
    half_t* QT  = KT + 512*20;      // [512 t][20], pre-scaled by 0.25*log2e
    half_t* FOs = QT + 512*20;      // [16 c][520]
    const int tid = threadIdx.x;
    const int b = blockIdx.x / FD, f = blockIdx.x % FD;
    const half_t* qbase = tq + (long)b*32*FT + (long)f*TD;
    const half_t* fbase = fo + (long)b*16*FT + (long)f*TD;
    const half_t qsc = (half_t)(0.25f*LOG2E);
    for (int idx = tid; idx < 16*128; idx += 512) {
        const int c = idx >> 7, y4 = (idx & 127)*4;
        half4 qv = {(half_t)0.f,(half_t)0.f,(half_t)0.f,(half_t)0.f};
        half4 kv = qv, fv = qv;
        if (y4 + 3 < TD) {   // TD%4==0: rows are either fully valid or fully pad
            qv = *(const half4*)(qbase + (long)(2*c  )*FT + y4);
            kv = *(const half4*)(qbase + (long)(2*c+1)*FT + y4);
            fv = *(const half4*)(fbase + (long)c*FT + y4);
        }
        #pragma unroll
        for (int e = 0; e < 4; ++e) {
            QT[(y4+e)*20 + c] = qv[e]*qsc;
            KT[(y4+e)*20 + c] = kv[e];
        }
        *(half4*)&FOs[c*520 + y4] = fv;
    }
    __syncthreads();
    const int w = tid >> 6, lane = tid & 63;
    const int lmod = lane & 15, ldiv = lane >> 4;
    const int tts[4] = {w, 15-w, 16+w, 31-w};
    #pragma unroll
    for (int i = 0; i < 4; ++i) {
        const int tt = tts[i];
        const int t0 = 16*tt;
        const half4 qb = *(const half4*)&QT[(t0+lmod)*20 + 4*ldiv];
        f32x4 o = {0.f,0.f,0.f,0.f};
        float m = NEGINF, l = 0.f;
        int yt = 0;
        // pairs of strictly-below-diagonal (unmasked) tiles
        for (; yt + 1 < tt; yt += 2) {
            const int y0 = 16*yt;
            const half4 ka0 = *(const half4*)&KT[(y0   +lmod)*20 + 4*ldiv];
            const half4 ka1 = *(const half4*)&KT[(y0+16+lmod)*20 + 4*ldiv];
            f32x4 s0 = __builtin_amdgcn_mfma_f32_16x16x16f16(
                ka0, qb, (f32x4){0.f,0.f,0.f,0.f}, 0, 0, 0);
            f32x4 s1 = __builtin_amdgcn_mfma_f32_16x16x16f16(
                ka1, qb, (f32x4){0.f,0.f,0.f,0.f}, 0, 0, 0);
            float mt = fmaxf(fmaxf(fmaxf(s0[0],s0[1]), fmaxf(s0[2],s0[3])),
                             fmaxf(fmaxf(s1[0],s1[1]), fmaxf(s1[2],s1[3])));
            mt = fmaxf(mt, __shfl_xor(mt, 16, 64));
            mt = fmaxf(mt, __shfl_xor(mt, 32, 64));
            const float mn = fmaxf(m, mt);
            const float alpha = EXP2F(m - mn);
            half4 pb0, pb1; float ps = 0.f;
            #pragma unroll
            for (int r = 0; r < 4; ++r) {
                const float p0 = EXP2F(s0[r] - mn);
                const float p1 = EXP2F(s1[r] - mn);
                pb0[r] = (half_t)p0; pb1[r] = (half_t)p1;
                ps += p0 + p1;
            }
            ps += __shfl_xor(ps, 16, 64);
            ps += __shfl_xor(ps, 32, 64);
            l = l*alpha + ps;  m = mn;
            o[0] *= alpha; o[1] *= alpha; o[2] *= alpha; o[3] *= alpha;
            const half4 fa0 = *(const half4*)&FOs[lmod*520 + y0      + 4*ldiv];
            const half4 fa1 = *(const half4*)&FOs[lmod*520 + y0 + 16 + 4*ldiv];
            o = __builtin_amdgcn_mfma_f32_16x16x16f16(fa0, pb0, o, 0, 0, 0);
            o = __builtin_amdgcn_mfma_f32_16x16x16f16(fa1, pb1, o, 0, 0, 0);
        }
        if (yt < tt) {
            // tail pair: full tile yt, diagonal tile yt+1 == tt (masked)
            const int y0 = 16*yt;
            const half4 ka0 = *(const half4*)&KT[(y0   +lmod)*20 + 4*ldiv];
            const half4 ka1 = *(const half4*)&KT[(y0+16+lmod)*20 + 4*ldiv];
            f32x4 s0 = __builtin_amdgcn_mfma_f32_16x16x16f16(
                ka0, qb, (f32x4){0.f,0.f,0.f,0.f}, 0, 0, 0);
            f32x4 s1 = __builtin_amdgcn_mfma_f32_16x16x16f16(
                ka1, qb, (f32x4){0.f,0.f,0.f,0.f}, 0, 0, 0);
            #pragma unroll
            for (int r = 0; r < 4; ++r)
                if (4*ldiv + r > lmod) s1[r] = NEGINF;
            float mt = fmaxf(fmaxf(fmaxf(s0[0],s0[1]), fmaxf(s0[2],s0[3])),
                             fmaxf(fmaxf(s1[0],s1[1]), fmaxf(s1[2],s1[3])));
            mt = fmaxf(mt, __shfl_xor(mt, 16, 64));
            mt = fmaxf(mt, __shfl_xor(mt, 32, 64));
            const float mn = fmaxf(m, mt);
            const float alpha = EXP2F(m - mn);
            half4 pb0, pb1; float ps = 0.f;
            #pragma unroll
            for (int r = 0; r < 4; ++r) {
                const float p0 = EXP2F(s0[r] - mn);
                const float p1 = EXP2F(s1[r] - mn);
                pb0[r] = (half_t)p0; pb1[r] = (half_t)p1;
                ps += p0 + p1;
            }
            ps += __shfl_xor(ps, 16, 64);
            ps += __shfl_xor(ps, 32, 64);
            l = l*alpha + ps;  m = mn;
            o[0] *= alpha; o[1] *= alpha; o[2] *= alpha; o[3] *= alpha;
            const half4 fa0 = *(const half4*)&FOs[lmod*520 + y0      + 4*ldiv];
            const half4 fa1 = *(const half4*)&FOs[lmod*520 + y0 + 16 + 4*ldiv];
            o = __builtin_amdgcn_mfma_f32_16x16x16f16(fa0, pb0, o, 0, 0, 0);
            o = __builtin_amdgcn_mfma_f32_16x16x16f16(fa1, pb1, o, 0, 0, 0);
        } else {
            // single diagonal tile yt == tt (masked)
            const int y0 = 16*tt;
            const half4 ka = *(const half4*)&KT[(y0+lmod)*20 + 4*ldiv];
            f32x4 s = __builtin_amdgcn_mfma_f32_16x16x16f16(
                ka, qb, (f32x4){0.f,0.f,0.f,0.f}, 0, 0, 0);
            #pragma unroll
            for (int r = 0; r < 4; ++r)
                if (4*ldiv + r > lmod) s[r] = NEGINF;
            float mt = fmaxf(fmaxf(s[0],s[1]), fmaxf(s[2],s[3]));
            mt = fmaxf(mt, __shfl_xor(mt, 16, 64));
            mt = fmaxf(mt, __shfl_xor(mt, 32, 64));
            const float mn = fmaxf(m, mt);
            const float alpha = EXP2F(m - mn);
            half4 pb; float ps = 0.f;
            #pragma unroll
            for (int r = 0; r < 4; ++r) {
                const float p = EXP2F(s[r] - mn);
                pb[r] = (half_t)p; ps += p;
            }
            ps += __shfl_xor(ps, 16, 64);
            ps += __shfl_xor(ps, 32, 64);
            l = l*alpha + ps;  m = mn;
            o[0] *= alpha; o[1] *= alpha; o[2] *= alpha; o[3] *= alpha;
            const half4 fa4 = *(const half4*)&FOs[lmod*520 + y0 + 4*ldiv];
            o = __builtin_amdgcn_mfma_f32_16x16x16f16(fa4, pb, o, 0, 0, 0);
        }
        const float inv = 1.f/l;
        const int t = t0 + lmod;
        if (t < TD) {
            #pragma unroll
            for (int r = 0; r < 4; ++r) {
                const int c = 4*ldiv + r;
                tout[((long)(b*16 + c)*FD + f)*TD + t] = o[r]*inv;
            }
        }
    }
}

// ---------------------------------------------------------------------------
// Stage 4: proj 16->64 + BN + PReLU + residual. cg-split, float4 streams.
// ---------------------------------------------------------------------------
__global__ __launch_bounds__(256) void proj_kernel(
    const float* __restrict__ tout, const float* __restrict__ x,
    const float* __restrict__ pw, const float* __restrict__ pb_,
    const float* __restrict__ pg, const float* __restrict__ pbe,
    const float* __restrict__ pm, const float* __restrict__ pv_,
    const float* __restrict__ pa,
    float* __restrict__ out)
{
    __shared__ float PW[32*16];
    __shared__ float PB[32];
    const int tid = threadIdx.x;
    const int cg   = blockIdx.x & 1;
    const int bidx = blockIdx.x >> 1;
    const int ob   = cg*32;
    for (int idx = tid; idx < 32*16; idx += 256) {
        const int ol = idx >> 4;
        const int o = ob + ol;
        PW[idx] = pw[o*16 + (idx & 15)]*(pg[o]*rsqrtf(pv_[o]+EPS));
    }
    if (tid < 32) {
        const int o = ob + tid;
        PB[tid] = (pb_[o]-pm[o])*(pg[o]*rsqrtf(pv_[o]+EPS)) + pbe[o];
    }
    __syncthreads();
    const float ap = pa[0];
    const int og = tid >> 6, lane = tid & 63;   // og 0..3: outputs ob+og*8 .. +8
    const int b  = bidx / 502;
    const int nb = bidx % 502;
    const long n0 = (long)nb*256 + lane*4;
    if (n0 >= FT) return;
    float4 acc[8];
    #pragma unroll
    for (int j = 0; j < 8; ++j) {
        const float bv = PB[og*8+j];
        acc[j] = make_float4(bv, bv, bv, bv);
    }
    const float* tb = tout + (long)b*16*FT + n0;
    for (int cc = 0; cc < 16; cc += 4) {
        const float* tc = tb + (long)cc*FT;
        const float4 t0 = *(const float4*)(tc);
        const float4 t1 = *(const float4*)(tc + FT);
        const float4 t2 = *(const float4*)(tc + 2*FT);
        const float4 t3 = *(const float4*)(tc + 3*FT);
        #pragma unroll
        for (int j = 0; j < 8; ++j) {
            const float4 wv = *(const float4*)&PW[(og*8+j)*16 + cc];
            acc[j].x += wv.x*t0.x + wv.y*t1.x + wv.z*t2.x + wv.w*t3.x;
            acc[j].y += wv.x*t0.y + wv.y*t1.y + wv.z*t2.y + wv.w*t3.y;
            acc[j].z += wv.x*t0.z + wv.y*t1.z + wv.z*t2.z + wv.w*t3.z;
            acc[j].w += wv.x*t0.w + wv.y*t1.w + wv.z*t2.w + wv.w*t3.w;
        }
    }
    #pragma unroll
    for (int j = 0; j < 8; ++j) {
        const int o = ob + og*8 + j;
        float4 v = acc[j];
        v.x = v.x >= 0.f ? v.x : ap*v.x;
        v.y = v.y >= 0.f ? v.y : ap*v.y;
        v.z = v.z >= 0.f ? v.z : ap*v.z;
        v.w = v.w >= 0.f ? v.w : ap*v.w;
        const long gi = (long)(b*64 + o)*FT + n0;
        const float4 xv = *(const float4*)(x + gi);
        v.x += xv.x; v.y += xv.y; v.z += xv.z; v.w += xv.w;
        *(float4*)(out + gi) = v;
    }
}

extern "C" void kernel_launch(void* const* d_in, const int* in_sizes, int n_in,
                              void* d_out, int out_size, void* d_ws, size_t ws_size,
                              hipStream_t stream)
{
    const float* x     = (const float*)d_in[0];
    const float* fw    = (const float*)d_in[1];
    const float* fb_   = (const float*)d_in[2];
    const float* fg    = (const float*)d_in[3];
    const float* fbe   = (const float*)d_in[4];
    const float* fm    = (const float*)d_in[5];
    const float* fv_   = (const float*)d_in[6];
    const float* fa    = (const float*)d_in[7];
    const float* tw    = (const float*)d_in[8];
    const float* tb_   = (const float*)d_in[9];
    const float* tg    = (const float*)d_in[10];
    const float* tbe   = (const float*)d_in[11];
    const float* tm    = (const float*)d_in[12];
    const float* tv_   = (const float*)d_in[13];
    const float* ta    = (const float*)d_in[14];
    const float* pw    = (const float*)d_in[15];
    const float* pb_   = (const float*)d_in[16];
    const float* pg    = (const float*)d_in[17];
    const float* pbe   = (const float*)d_in[18];
    const float* pm    = (const float*)d_in[19];
    const float* pv_   = (const float*)d_in[20];
    const float* pa    = (const float*)d_in[21];
    float* out = (float*)d_out;

    // Workspace layout (bytes):
    //  A: fqh  f16 [2][48][FT]           24,672,000   (foT f32 [2][16][TD][260]=16,640,000 aliases after T1)
    //  B: foh  f16 [2][16][FT]            8,224,000
    //  C: tqh  f16 [2][32][FT]           16,448,000
    //  D: fqTh f16 [96][FQT_PLANE]       24,960,000   (tout f32 [2][16][FT] aliases after fattn)
    char* base = (char*)d_ws;
    const size_t szA = (size_t)BB*48*FT*sizeof(half_t);
    const size_t szB = (size_t)BB*16*FT*sizeof(half_t);
    const size_t szC = (size_t)BB*32*FT*sizeof(half_t);
    const size_t szD = (size_t)96*FQT_PLANE*sizeof(half_t);
    const size_t need = szA + szB + szC + szD;   // 74,304,000
    if (ws_size < need) return;
    half_t* fqh  = (half_t*)base;
    float*  foT  = (float*)base;                 // alias A
    half_t* foh  = (half_t*)(base + szA);
    half_t* tqh  = (half_t*)(base + szA + szB);
    half_t* fqTh = (half_t*)(base + szA + szB + szC);
    float*  tout = (float*)(base + szA + szB + szC);  // alias D

    stage1_kernel<<<dim3(BB*1004), dim3(256), 0, stream>>>(
        x, fw, fb_, fg, fbe, fm, fv_, fa, tw, tb_, tg, tbe, tm, tv_, ta, fqh, tqh);

    // T1: fq[b][c][f][t] -> fqT[b][c][t][f(pad 260)]
    transpose_h2h_kernel<<<dim3(BB*48, 5, 8), dim3(256), 0, stream>>>(
        fqh, fqTh, FD, TD, FDP);

    fattn_kernel<<<dim3(BB*TD), dim3(512), 0, stream>>>(fqTh, foT);

    // T2: foT[b][c][t][f(pad 260)] (f32) -> fo[b][c][f][t] (f16)
    transpose_f2h_kernel<<<dim3(BB*16, 8, 5), dim3(256), 0, stream>>>(
        foT, foh, TD, FD, FDP4, TD);

    const int tlds = (512*20*2 + 16*520)*(int)sizeof(half_t);  // 57,600 B
    (void)hipFuncSetAttribute(reinterpret_cast<const void*>(tattn_kernel),
                        hipFuncAttributeMaxDynamicSharedMemorySize, tlds);
    tattn_kernel<<<dim3(BB*FD), dim3(512), tlds, stream>>>(tqh, foh, tout);

    proj_kernel<<<dim3(BB*502*2), dim3(256), 0, stream>>>(
        tout, x, pw, pb_, pg, pbe, pm, pv_, pa, out);
}

// Round 8
// 285.195 us; speedup vs baseline: 1.0269x; 1.0269x over previous
//
#include <hip/hip_runtime.h>

#define BB 2
#define CIN 64
#define FD 257
#define TD 500
#define FT (FD*TD)      // 128500
#define EPS 1e-5f
#define NEGINF (-3.0e38f)
#define FDP 260         // padded row length (halves, 8B-aligned rows)
#define FQT_PLANE (TD*FDP)   // 130000 halves per (b,channel) plane
#define FOT_PLANE (TD*FDP)   // foT f16 [t][f pad 260] plane
#define LOG2E 1.44269504088896f
#define EXP2F(x) __builtin_amdgcn_exp2f(x)

typedef _Float16 half_t;
typedef half_t half2_t __attribute__((ext_vector_type(2)));
typedef half_t half4 __attribute__((ext_vector_type(4)));
typedef float  f32x4 __attribute__((ext_vector_type(4)));

// ---------------------------------------------------------------------------
// Stage 1 (MFMA): out[80, FT] = W[80,64] . x[64, FT], fused BN fold + PReLU.
// Round-6 form (best measured: 52.8us): scalar global loads direct to MFMA
// B-fragments; epilogue bounces through per-wave LDS slab [32 p][80 o] so
// global stores are 10 half4 full-line stores. (Round-7 LDS-staged loads
// regressed to 60us -> reverted.)
// ---------------------------------------------------------------------------
__global__ __launch_bounds__(256) void stage1_kernel(
    const float* __restrict__ x,
    const float* __restrict__ fw, const float* __restrict__ fb_,
    const float* __restrict__ fg, const float* __restrict__ fbe,
    const float* __restrict__ fm, const float* __restrict__ fv_,
    const float* __restrict__ fa,
    const float* __restrict__ tw, const float* __restrict__ tb_,
    const float* __restrict__ tg, const float* __restrict__ tbe,
    const float* __restrict__ tm, const float* __restrict__ tv_,
    const float* __restrict__ ta,
    half_t* __restrict__ fq, half_t* __restrict__ tq)
{
    __shared__ half_t Wh[80][68];     // folded weights, f16
    __shared__ float  Bl[80];         // folded bias
    __shared__ half_t Ob[4][32][80];  // per-wave out slab [p][o], o XOR-swizzled
    const int tid = threadIdx.x;
    for (int idx = tid; idx < 80*64; idx += 256) {
        const int o = idx >> 6, i = idx & 63;
        float sc, wv;
        if (o < 48) { sc = fg[o]*rsqrtf(fv_[o]+EPS); wv = fw[o*64+i]; }
        else { const int o2 = o-48; sc = tg[o2]*rsqrtf(tv_[o2]+EPS); wv = tw[o2*64+i]; }
        Wh[o][i] = (half_t)(wv*sc);
    }
    if (tid < 80) {
        const int o = tid;
        if (o < 48) Bl[o] = (fb_[o]-fm[o])*(fg[o]*rsqrtf(fv_[o]+EPS)) + fbe[o];
        else { const int o2 = o-48; Bl[o] = (tb_[o2]-tm[o2])*(tg[o2]*rsqrtf(tv_[o2]+EPS)) + tbe[o2]; }
    }
    __syncthreads();
    const float af = fa[0], at = ta[0];
    const int w = tid >> 6, lane = tid & 63;
    const int lmod = lane & 15, ldiv = lane >> 4;
    const int b  = blockIdx.x / 1004;
    const int nb = blockIdx.x % 1004;
    const long n0 = (long)nb*128;

    // A fragments: a[ot][ks] = Wh[16*ot + lmod][16*ks + 4*ldiv .. +3]
    half4 a[5][4];
    #pragma unroll
    for (int ot = 0; ot < 5; ++ot)
        #pragma unroll
        for (int ks = 0; ks < 4; ++ks)
            a[ot][ks] = *(const half4*)&Wh[16*ot + lmod][16*ks + 4*ldiv];
    f32x4 bias[5];
    #pragma unroll
    for (int ot = 0; ot < 5; ++ot)
        #pragma unroll
        for (int r = 0; r < 4; ++r)
            bias[ot][r] = Bl[16*ot + 4*ldiv + r];

    const float* xplane = x + (long)b*CIN*FT;
    // B fragments for BOTH position sub-tiles issued up-front (more MLP).
    half4 bfr[2][4];
    #pragma unroll
    for (int pt = 0; pt < 2; ++pt) {
        const long p = n0 + 32*w + 16*pt + lmod;
        const long pc = (p < FT) ? p : (FT-1);   // clamp; value unused when OOB
        const float* xp = xplane + pc;
        #pragma unroll
        for (int ks = 0; ks < 4; ++ks) {
            #pragma unroll
            for (int e = 0; e < 4; ++e) {
                const int ch = 16*ks + 4*ldiv + e;
                bfr[pt][ks][e] = (half_t)xp[(long)ch*FT];
            }
        }
    }
    #pragma unroll
    for (int pt = 0; pt < 2; ++pt) {
        const int pl = 16*pt + lmod;
        const int msk = ((pl >> 2) & 3) << 2;    // bits 2-3: stays in 16-group
        #pragma unroll
        for (int ot = 0; ot < 5; ++ot) {
            f32x4 acc = bias[ot];
            #pragma unroll
            for (int ks = 0; ks < 4; ++ks)
                acc = __builtin_amdgcn_mfma_f32_16x16x16f16(a[ot][ks], bfr[pt][ks], acc, 0, 0, 0);
            const float alpha = (ot < 3) ? af : at;
            half4 hv;
            #pragma unroll
            for (int r = 0; r < 4; ++r) {
                float v = acc[r];
                v = v >= 0.f ? v : alpha*v;
                hv[r] = (half_t)v;
            }
            // element o=16ot+4ldiv+r lands at col o^msk (msk has no bits 0-1)
            *(half4*)&Ob[w][pl][(16*ot + 4*ldiv) ^ msk] = hv;
        }
    }
    // Store phase: wave-local (no barrier needed; same-wave LDS ordering).
    const int pr = lane & 7, og0 = lane >> 3;
    const long pbase = n0 + 32*w + 4*pr;
    if (pbase < FT) {    // FT%4==0: half4 chunks are all-or-nothing valid
        const int msk = (pr & 3) << 2;           // row 4*pr+e -> (p>>2)&3 == pr&3
        #pragma unroll
        for (int i = 0; i < 10; ++i) {
            const int o = og0 + 8*i;
            half4 hv;
            #pragma unroll
            for (int e = 0; e < 4; ++e) hv[e] = Ob[w][4*pr + e][o ^ msk];
            half_t* dst = (o < 48) ? (fq + ((long)b*48 + o)*FT + pbase)
                                   : (tq + ((long)b*32 + (o-48))*FT + pbase);
            *(half4*)dst = hv;
        }
    }
}

// ---------------------------------------------------------------------------
// Transpose (f16->f16): src[plane][R][CS(row stride)] logical [R][C] ->
// dst[plane][C][RP], pad r in [R,RP) zeroed. 64x64 tile; half4 (8B/lane)
// global access on BOTH sides.
// ---------------------------------------------------------------------------
__global__ __launch_bounds__(256) void transpose_h2h_kernel(
    const half_t* __restrict__ src, half_t* __restrict__ dst,
    int R, int C, int CS, int RP)
{
    __shared__ half_t tile[64][68];
    const int plane = blockIdx.x;
    const int rb = blockIdx.y*64, cb = blockIdx.z*64;
    const half_t* s = src + (long)plane*R*CS;
    half_t* d = dst + (long)plane*C*RP;
    const int q4 = (threadIdx.x & 15)*4;   // 0..60
    const int wl = threadIdx.x >> 4;       // 0..15
    #pragma unroll
    for (int p = 0; p < 4; ++p) {
        const int r = rb + wl + 16*p;
        const int c = cb + q4;
        half4 v = {(half_t)0.f,(half_t)0.f,(half_t)0.f,(half_t)0.f};
        if (r < R) {
            const half_t* srow = s + (long)r*CS;
            if (c + 3 < C) v = *(const half4*)(srow + c);
            else {
                #pragma unroll
                for (int e = 0; e < 4; ++e) if (c+e < C) v[e] = srow[c+e];
            }
        }
        *(half4*)&tile[wl + 16*p][q4] = v;
    }
    __syncthreads();
    #pragma unroll
    for (int p = 0; p < 4; ++p) {
        const int c = cb + wl + 16*p;
        if (c >= C) continue;
        const int r0 = rb + q4;
        half4 o;
        #pragma unroll
        for (int e = 0; e < 4; ++e) o[e] = tile[q4 + e][wl + 16*p];
        half_t* drow = d + (long)c*RP;
        if (r0 + 3 < RP) *(half4*)(drow + r0) = o;
        else {
            #pragma unroll
            for (int e = 0; e < 4; ++e) if (r0+e < RP) drow[r0+e] = o[e];
        }
    }
}

// ---------------------------------------------------------------------------
// Stage 2: frequency attention, MFMA flash-style. One block per (b,t),
// 512 threads (8 waves). Paired K-tiles per softmax update; exp2 with
// log2e folded into Q scale. Output f16 (T2 casts to f16 anyway — same
// single rounding from the same f32 value, bit-identical) into padded
// [t][f pad 260] rows -> halves fattn write + T2 read traffic.
// ---------------------------------------------------------------------------
__global__ __launch_bounds__(512) void fattn_kernel(
    const half_t* __restrict__ fqT, half_t* __restrict__ foT)
{
    __shared__ half_t KT[272*20];   // [y][c]
    __shared__ half_t QT[272*20];   // [f][c], pre-scaled by 0.25*log2e
    __shared__ half_t Vs[16*280];   // [c][y]
    const int tid = threadIdx.x;
    const int b = blockIdx.x / TD, t = blockIdx.x % TD;
    const half_t* base = fqT + (long)b*48*FQT_PLANE + (long)t*FDP;
    const half_t qsc = (half_t)(0.25f*LOG2E);
    for (int s = tid; s < 48*68; s += 512) {
        const int c3 = s / 68, j = s - c3*68;
        const int f0 = 4*j;
        half4 v = {(half_t)0.f,(half_t)0.f,(half_t)0.f,(half_t)0.f};
        if (f0 < FDP) v = *(const half4*)(base + (long)c3*FQT_PLANE + f0);
        const int c = c3 / 3, wh = c3 - 3*c;   // q=3c, k=3c+1, v=3c+2
        if (wh == 0) {
            #pragma unroll
            for (int e = 0; e < 4; ++e) QT[(f0+e)*20 + c] = v[e]*qsc;
        } else if (wh == 1) {
            #pragma unroll
            for (int e = 0; e < 4; ++e) KT[(f0+e)*20 + c] = v[e];
        } else {
            *(half4*)&Vs[c*280 + f0] = v;
        }
    }
    __syncthreads();
    const int w = tid >> 6, lane = tid & 63;
    const int lmod = lane & 15, ldiv = lane >> 4;
    for (int ft = w; ft < 17; ft += 8) {    // w=0: {0,8,16}; others {w, w+8}
        const int f0 = 16*ft;
        const half4 qb = *(const half4*)&QT[(f0+lmod)*20 + 4*ldiv];
        f32x4 o = {0.f,0.f,0.f,0.f};
        float m = NEGINF, l = 0.f;
        // 8 pairs of full tiles: y = 0..255, all < FD
        for (int yt = 0; yt < 16; yt += 2) {
            const int y0 = 16*yt;
            const half4 ka0 = *(const half4*)&KT[(y0   +lmod)*20 + 4*ldiv];
            const half4 ka1 = *(const half4*)&KT[(y0+16+lmod)*20 + 4*ldiv];
            f32x4 s0 = __builtin_amdgcn_mfma_f32_16x16x16f16(
                ka0, qb, (f32x4){0.f,0.f,0.f,0.f}, 0, 0, 0);
            f32x4 s1 = __builtin_amdgcn_mfma_f32_16x16x16f16(
                ka1, qb, (f32x4){0.f,0.f,0.f,0.f}, 0, 0, 0);
            float mt = fmaxf(fmaxf(fmaxf(s0[0],s0[1]), fmaxf(s0[2],s0[3])),
                             fmaxf(fmaxf(s1[0],s1[1]), fmaxf(s1[2],s1[3])));
            mt = fmaxf(mt, __shfl_xor(mt, 16, 64));
            mt = fmaxf(mt, __shfl_xor(mt, 32, 64));
            const float mn = fmaxf(m, mt);
            const float alpha = EXP2F(m - mn);
            half4 pb0, pb1; float ps = 0.f;
            #pragma unroll
            for (int r = 0; r < 4; ++r) {
                const float p0 = EXP2F(s0[r] - mn);
                const float p1 = EXP2F(s1[r] - mn);
                pb0[r] = (half_t)p0; pb1[r] = (half_t)p1;
                ps += p0 + p1;
            }
            ps += __shfl_xor(ps, 16, 64);
            ps += __shfl_xor(ps, 32, 64);
            l = l*alpha + ps;  m = mn;
            o[0] *= alpha; o[1] *= alpha; o[2] *= alpha; o[3] *= alpha;
            const half4 va0 = *(const half4*)&Vs[lmod*280 + y0      + 4*ldiv];
            const half4 va1 = *(const half4*)&Vs[lmod*280 + y0 + 16 + 4*ldiv];
            o = __builtin_amdgcn_mfma_f32_16x16x16f16(va0, pb0, o, 0, 0, 0);
            o = __builtin_amdgcn_mfma_f32_16x16x16f16(va1, pb1, o, 0, 0, 0);
        }
        {   // tail tile yt=16: y = 256..271, mask y >= FD
            const int y0 = 256;
            const half4 ka = *(const half4*)&KT[(y0+lmod)*20 + 4*ldiv];
            f32x4 s = __builtin_amdgcn_mfma_f32_16x16x16f16(
                ka, qb, (f32x4){0.f,0.f,0.f,0.f}, 0, 0, 0);
            #pragma unroll
            for (int r = 0; r < 4; ++r)
                if (y0 + 4*ldiv + r >= FD) s[r] = NEGINF;
            float mt = fmaxf(fmaxf(s[0],s[1]), fmaxf(s[2],s[3]));
            mt = fmaxf(mt, __shfl_xor(mt, 16, 64));
            mt = fmaxf(mt, __shfl_xor(mt, 32, 64));
            const float mn = fmaxf(m, mt);
            const float alpha = EXP2F(m - mn);
            half4 pb; float ps = 0.f;
            #pragma unroll
            for (int r = 0; r < 4; ++r) {
                const float p = EXP2F(s[r] - mn);
                pb[r] = (half_t)p; ps += p;
            }
            ps += __shfl_xor(ps, 16, 64);
            ps += __shfl_xor(ps, 32, 64);
            l = l*alpha + ps;  m = mn;
            o[0] *= alpha; o[1] *= alpha; o[2] *= alpha; o[3] *= alpha;
            const half4 va = *(const half4*)&Vs[lmod*280 + y0 + 4*ldiv];
            o = __builtin_amdgcn_mfma_f32_16x16x16f16(va, pb, o, 0, 0, 0);
        }
        const float inv = 1.f/l;
        const int f = f0 + lmod;
        if (f < FD) {
            #pragma unroll
            for (int r = 0; r < 4; ++r) {
                const int c = 4*ldiv + r;
                foT[((long)(b*16 + c)*TD + t)*FDP + f] = (half_t)(o[r]*inv);
            }
        }
    }
}

// ---------------------------------------------------------------------------
// Stage 3: causal time attention. One block per (b,f), 512 threads (8 waves).
// half4 vectorized loads; paired K-tiles; exp2 with log2e folded into Q scale.
// ---------------------------------------------------------------------------
__global__ __launch_bounds__(512) void tattn_kernel(
    const half_t* __restrict__ tq, const half_t* __restrict__ fo,
    float* __restrict__ tout)
{
    extern __shared__ half_t lds[];
    half_t* KT  = lds;              // [512 y][20]
    half_t* QT  = KT + 512*20;      // [512 t][20], pre-scaled by 0.25*log2e
    half_t* FOs = QT + 512*20;      // [16 c][520]
    const int tid = threadIdx.x;
    const int b = blockIdx.x / FD, f = blockIdx.x % FD;
    const half_t* qbase = tq + (long)b*32*FT + (long)f*TD;
    const half_t* fbase = fo + (long)b*16*FT + (long)f*TD;
    const half_t qsc = (half_t)(0.25f*LOG2E);
    for (int idx = tid; idx < 16*128; idx += 512) {
        const int c = idx >> 7, y4 = (idx & 127)*4;
        half4 qv = {(half_t)0.f,(half_t)0.f,(half_t)0.f,(half_t)0.f};
        half4 kv = qv, fv = qv;
        if (y4 + 3 < TD) {   // TD%4==0: rows are either fully valid or fully pad
            qv = *(const half4*)(qbase + (long)(2*c  )*FT + y4);
            kv = *(const half4*)(qbase + (long)(2*c+1)*FT + y4);
            fv = *(const half4*)(fbase + (long)c*FT + y4);
        }
        #pragma unroll
        for (int e = 0; e < 4; ++e) {
            QT[(y4+e)*20 + c] = qv[e]*qsc;
            KT[(y4+e)*20 + c] = kv[e];
        }
        *(half4*)&FOs[c*520 + y4] = fv;
    }
    __syncthreads();
    const int w = tid >> 6, lane = tid & 63;
    const int lmod = lane & 15, ldiv = lane >> 4;
    const int tts[4] = {w, 15-w, 16+w, 31-w};
    #pragma unroll
    for (int i = 0; i < 4; ++i) {
        const int tt = tts[i];
        const int t0 = 16*tt;
        const half4 qb = *(const half4*)&QT[(t0+lmod)*20 + 4*ldiv];
        f32x4 o = {0.f,0.f,0.f,0.f};
        float m = NEGINF, l = 0.f;
        int yt = 0;
        // pairs of strictly-below-diagonal (unmasked) tiles
        for (; yt + 1 < tt; yt += 2) {
            const int y0 = 16*yt;
            const half4 ka0 = *(const half4*)&KT[(y0   +lmod)*20 + 4*ldiv];
            const half4 ka1 = *(const half4*)&KT[(y0+16+lmod)*20 + 4*ldiv];
            f32x4 s0 = __builtin_amdgcn_mfma_f32_16x16x16f16(
                ka0, qb, (f32x4){0.f,0.f,0.f,0.f}, 0, 0, 0);
            f32x4 s1 = __builtin_amdgcn_mfma_f32_16x16x16f16(
                ka1, qb, (f32x4){0.f,0.f,0.f,0.f}, 0, 0, 0);
            float mt = fmaxf(fmaxf(fmaxf(s0[0],s0[1]), fmaxf(s0[2],s0[3])),
                             fmaxf(fmaxf(s1[0],s1[1]), fmaxf(s1[2],s1[3])));
            mt = fmaxf(mt, __shfl_xor(mt, 16, 64));
            mt = fmaxf(mt, __shfl_xor(mt, 32, 64));
            const float mn = fmaxf(m, mt);
            const float alpha = EXP2F(m - mn);
            half4 pb0, pb1; float ps = 0.f;
            #pragma unroll
            for (int r = 0; r < 4; ++r) {
                const float p0 = EXP2F(s0[r] - mn);
                const float p1 = EXP2F(s1[r] - mn);
                pb0[r] = (half_t)p0; pb1[r] = (half_t)p1;
                ps += p0 + p1;
            }
            ps += __shfl_xor(ps, 16, 64);
            ps += __shfl_xor(ps, 32, 64);
            l = l*alpha + ps;  m = mn;
            o[0] *= alpha; o[1] *= alpha; o[2] *= alpha; o[3] *= alpha;
            const half4 fa0 = *(const half4*)&FOs[lmod*520 + y0      + 4*ldiv];
            const half4 fa1 = *(const half4*)&FOs[lmod*520 + y0 + 16 + 4*ldiv];
            o = __builtin_amdgcn_mfma_f32_16x16x16f16(fa0, pb0, o, 0, 0, 0);
            o = __builtin_amdgcn_mfma_f32_16x16x16f16(fa1, pb1, o, 0, 0, 0);
        }
        if (yt < tt) {
            // tail pair: full tile yt, diagonal tile yt+1 == tt (masked)
            const int y0 = 16*yt;
            const half4 ka0 = *(const half4*)&KT[(y0   +lmod)*20 + 4*ldiv];
            const half4 ka1 = *(const half4*)&KT[(y0+16+lmod)*20 + 4*ldiv];
            f32x4 s0 = __builtin_amdgcn_mfma_f32_16x16x16f16(
                ka0, qb, (f32x4){0.f,0.f,0.f,0.f}, 0, 0, 0);
            f32x4 s1 = __builtin_amdgcn_mfma_f32_16x16x16f16(
                ka1, qb, (f32x4){0.f,0.f,0.f,0.f}, 0, 0, 0);
            #pragma unroll
            for (int r = 0; r < 4; ++r)
                if (4*ldiv + r > lmod) s1[r] = NEGINF;
            float mt = fmaxf(fmaxf(fmaxf(s0[0],s0[1]), fmaxf(s0[2],s0[3])),
                             fmaxf(fmaxf(s1[0],s1[1]), fmaxf(s1[2],s1[3])));
            mt = fmaxf(mt, __shfl_xor(mt, 16, 64));
            mt = fmaxf(mt, __shfl_xor(mt, 32, 64));
            const float mn = fmaxf(m, mt);
            const float alpha = EXP2F(m - mn);
            half4 pb0, pb1; float ps = 0.f;
            #pragma unroll
            for (int r = 0; r < 4; ++r) {
                const float p0 = EXP2F(s0[r] - mn);
                const float p1 = EXP2F(s1[r] - mn);
                pb0[r] = (half_t)p0; pb1[r] = (half_t)p1;
                ps += p0 + p1;
            }
            ps += __shfl_xor(ps, 16, 64);
            ps += __shfl_xor(ps, 32, 64);
            l = l*alpha + ps;  m = mn;
            o[0] *= alpha; o[1] *= alpha; o[2] *= alpha; o[3] *= alpha;
            const half4 fa0 = *(const half4*)&FOs[lmod*520 + y0      + 4*ldiv];
            const half4 fa1 = *(const half4*)&FOs[lmod*520 + y0 + 16 + 4*ldiv];
            o = __builtin_amdgcn_mfma_f32_16x16x16f16(fa0, pb0, o, 0, 0, 0);
            o = __builtin_amdgcn_mfma_f32_16x16x16f16(fa1, pb1, o, 0, 0, 0);
        } else {
            // single diagonal tile yt == tt (masked)
            const int y0 = 16*tt;
            const half4 ka = *(const half4*)&KT[(y0+lmod)*20 + 4*ldiv];
            f32x4 s = __builtin_amdgcn_mfma_f32_16x16x16f16(
                ka, qb, (f32x4){0.f,0.f,0.f,0.f}, 0, 0, 0);
            #pragma unroll
            for (int r = 0; r < 4; ++r)
                if (4*ldiv + r > lmod) s[r] = NEGINF;
            float mt = fmaxf(fmaxf(s[0],s[1]), fmaxf(s[2],s[3]));
            mt = fmaxf(mt, __shfl_xor(mt, 16, 64));
            mt = fmaxf(mt, __shfl_xor(mt, 32, 64));
            const float mn = fmaxf(m, mt);
            const float alpha = EXP2F(m - mn);
            half4 pb; float ps = 0.f;
            #pragma unroll
            for (int r = 0; r < 4; ++r) {
                const float p = EXP2F(s[r] - mn);
                pb[r] = (half_t)p; ps += p;
            }
            ps += __shfl_xor(ps, 16, 64);
            ps += __shfl_xor(ps, 32, 64);
            l = l*alpha + ps;  m = mn;
            o[0] *= alpha; o[1] *= alpha; o[2] *= alpha; o[3] *= alpha;
            const half4 fa4 = *(const half4*)&FOs[lmod*520 + y0 + 4*ldiv];
            o = __builtin_amdgcn_mfma_f32_16x16x16f16(fa4, pb, o, 0, 0, 0);
        }
        const float inv = 1.f/l;
        const int t = t0 + lmod;
        if (t < TD) {
            #pragma unroll
            for (int r = 0; r < 4; ++r) {
                const int c = 4*ldiv + r;
                tout[((long)(b*16 + c)*FD + f)*TD + t] = o[r]*inv;
            }
        }
    }
}

// ---------------------------------------------------------------------------
// Stage 4: proj 16->64 + BN + PReLU + residual. cg-split, float4 streams.
// ---------------------------------------------------------------------------
__global__ __launch_bounds__(256) void proj_kernel(
    const float* __restrict__ tout, const float* __restrict__ x,
    const float* __restrict__ pw, const float* __restrict__ pb_,
    const float* __restrict__ pg, const float* __restrict__ pbe,
    const float* __restrict__ pm, const float* __restrict__ pv_,
    const float* __restrict__ pa,
    float* __restrict__ out)
{
    __shared__ float PW[32*16];
    __shared__ float PB[32];
    const int tid = threadIdx.x;
    const int cg   = blockIdx.x & 1;
    const int bidx = blockIdx.x >> 1;
    const int ob   = cg*32;
    for (int idx = tid; idx < 32*16; idx += 256) {
        const int ol = idx >> 4;
        const int o = ob + ol;
        PW[idx] = pw[o*16 + (idx & 15)]*(pg[o]*rsqrtf(pv_[o]+EPS));
    }
    if (tid < 32) {
        const int o = ob + tid;
        PB[tid] = (pb_[o]-pm[o])*(pg[o]*rsqrtf(pv_[o]+EPS)) + pbe[o];
    }
    __syncthreads();
    const float ap = pa[0];
    const int og = tid >> 6, lane = tid & 63;   // og 0..3: outputs ob+og*8 .. +8
    const int b  = bidx / 502;
    const int nb = bidx % 502;
    const long n0 = (long)nb*256 + lane*4;
    if (n0 >= FT) return;
    float4 acc[8];
    #pragma unroll
    for (int j = 0; j < 8; ++j) {
        const float bv = PB[og*8+j];
        acc[j] = make_float4(bv, bv, bv, bv);
    }
    const float* tb = tout + (long)b*16*FT + n0;
    for (int cc = 0; cc < 16; cc += 4) {
        const float* tc = tb + (long)cc*FT;
        const float4 t0 = *(const float4*)(tc);
        const float4 t1 = *(const float4*)(tc + FT);
        const float4 t2 = *(const float4*)(tc + 2*FT);
        const float4 t3 = *(const float4*)(tc + 3*FT);
        #pragma unroll
        for (int j = 0; j < 8; ++j) {
            const float4 wv = *(const float4*)&PW[(og*8+j)*16 + cc];
            acc[j].x += wv.x*t0.x + wv.y*t1.x + wv.z*t2.x + wv.w*t3.x;
            acc[j].y += wv.x*t0.y + wv.y*t1.y + wv.z*t2.y + wv.w*t3.y;
            acc[j].z += wv.x*t0.z + wv.y*t1.z + wv.z*t2.z + wv.w*t3.z;
            acc[j].w += wv.x*t0.w + wv.y*t1.w + wv.z*t2.w + wv.w*t3.w;
        }
    }
    #pragma unroll
    for (int j = 0; j < 8; ++j) {
        const int o = ob + og*8 + j;
        float4 v = acc[j];
        v.x = v.x >= 0.f ? v.x : ap*v.x;
        v.y = v.y >= 0.f ? v.y : ap*v.y;
        v.z = v.z >= 0.f ? v.z : ap*v.z;
        v.w = v.w >= 0.f ? v.w : ap*v.w;
        const long gi = (long)(b*64 + o)*FT + n0;
        const float4 xv = *(const float4*)(x + gi);
        v.x += xv.x; v.y += xv.y; v.z += xv.z; v.w += xv.w;
        *(float4*)(out + gi) = v;
    }
}

extern "C" void kernel_launch(void* const* d_in, const int* in_sizes, int n_in,
                              void* d_out, int out_size, void* d_ws, size_t ws_size,
                              hipStream_t stream)
{
    const float* x     = (const float*)d_in[0];
    const float* fw    = (const float*)d_in[1];
    const float* fb_   = (const float*)d_in[2];
    const float* fg    = (const float*)d_in[3];
    const float* fbe   = (const float*)d_in[4];
    const float* fm    = (const float*)d_in[5];
    const float* fv_   = (const float*)d_in[6];
    const float* fa    = (const float*)d_in[7];
    const float* tw    = (const float*)d_in[8];
    const float* tb_   = (const float*)d_in[9];
    const float* tg    = (const float*)d_in[10];
    const float* tbe   = (const float*)d_in[11];
    const float* tm    = (const float*)d_in[12];
    const float* tv_   = (const float*)d_in[13];
    const float* ta    = (const float*)d_in[14];
    const float* pw    = (const float*)d_in[15];
    const float* pb_   = (const float*)d_in[16];
    const float* pg    = (const float*)d_in[17];
    const float* pbe   = (const float*)d_in[18];
    const float* pm    = (const float*)d_in[19];
    const float* pv_   = (const float*)d_in[20];
    const float* pa    = (const float*)d_in[21];
    float* out = (float*)d_out;

    // Workspace layout (bytes):
    //  A: fqh  f16 [2][48][FT]           24,672,000   (foTh f16 [2][16][TD][260]=8,320,000 aliases after T1)
    //  B: foh  f16 [2][16][FT]            8,224,000
    //  C: tqh  f16 [2][32][FT]           16,448,000
    //  D: fqTh f16 [96][FQT_PLANE]       24,960,000   (tout f32 [2][16][FT] aliases after fattn)
    char* base = (char*)d_ws;
    const size_t szA = (size_t)BB*48*FT*sizeof(half_t);
    const size_t szB = (size_t)BB*16*FT*sizeof(half_t);
    const size_t szC = (size_t)BB*32*FT*sizeof(half_t);
    const size_t szD = (size_t)96*FQT_PLANE*sizeof(half_t);
    const size_t need = szA + szB + szC + szD;   // 74,304,000
    if (ws_size < need) return;
    half_t* fqh  = (half_t*)base;
    half_t* foTh = (half_t*)base;                // alias A (8.32 MB < szA)
    half_t* foh  = (half_t*)(base + szA);
    half_t* tqh  = (half_t*)(base + szA + szB);
    half_t* fqTh = (half_t*)(base + szA + szB + szC);
    float*  tout = (float*)(base + szA + szB + szC);  // alias D

    stage1_kernel<<<dim3(BB*1004), dim3(256), 0, stream>>>(
        x, fw, fb_, fg, fbe, fm, fv_, fa, tw, tb_, tg, tbe, tm, tv_, ta, fqh, tqh);

    // T1: fq[b][c][f][t] -> fqT[b][c][t][f(pad 260)]
    transpose_h2h_kernel<<<dim3(BB*48, 5, 8), dim3(256), 0, stream>>>(
        fqh, fqTh, FD, TD, TD, FDP);

    fattn_kernel<<<dim3(BB*TD), dim3(512), 0, stream>>>(fqTh, foTh);

    // T2: foT[b][c][t][f(pad 260)] (f16) -> fo[b][c][f][t] (f16)
    transpose_h2h_kernel<<<dim3(BB*16, 8, 5), dim3(256), 0, stream>>>(
        foTh, foh, TD, FD, FDP, TD);

    const int tlds = (512*20*2 + 16*520)*(int)sizeof(half_t);  // 57,600 B
    (void)hipFuncSetAttribute(reinterpret_cast<const void*>(tattn_kernel),
                        hipFuncAttributeMaxDynamicSharedMemorySize, tlds);
    tattn_kernel<<<dim3(BB*FD), dim3(512), tlds, stream>>>(tqh, foh, tout);

    proj_kernel<<<dim3(BB*502*2), dim3(256), 0, stream>>>(
        tout, x, pw, pb_, pg, pbe, pm, pv_, pa, out);
}

// Round 9
// 281.160 us; speedup vs baseline: 1.0417x; 1.0144x over previous
//
#include <hip/hip_runtime.h>

#define BB 2
#define CIN 64
#define FD 257
#define TD 500
#define FT (FD*TD)      // 128500
#define EPS 1e-5f
#define NEGINF (-3.0e38f)
#define FDP 260         // padded row length (halves, 8B-aligned rows)
#define FQT_PLANE (TD*FDP)   // 130000 halves per (b,channel) plane
#define LOG2E 1.44269504088896f
#define EXP2F(x) __builtin_amdgcn_exp2f(x)

typedef _Float16 half_t;
typedef half_t half2_t __attribute__((ext_vector_type(2)));
typedef half_t half4 __attribute__((ext_vector_type(4)));
typedef float  f32x4 __attribute__((ext_vector_type(4)));

// ---------------------------------------------------------------------------
// Stage 1 (MFMA): out[80, FT] = W[80,64] . x[64, FT], fused BN fold + PReLU.
// Round-6 form (best measured: ~52us): scalar global loads direct to MFMA
// B-fragments; epilogue bounces through per-wave LDS slab [32 p][80 o] so
// global stores are 10 half4 full-line stores.
// ---------------------------------------------------------------------------
__global__ __launch_bounds__(256) void stage1_kernel(
    const float* __restrict__ x,
    const float* __restrict__ fw, const float* __restrict__ fb_,
    const float* __restrict__ fg, const float* __restrict__ fbe,
    const float* __restrict__ fm, const float* __restrict__ fv_,
    const float* __restrict__ fa,
    const float* __restrict__ tw, const float* __restrict__ tb_,
    const float* __restrict__ tg, const float* __restrict__ tbe,
    const float* __restrict__ tm, const float* __restrict__ tv_,
    const float* __restrict__ ta,
    half_t* __restrict__ fq, half_t* __restrict__ tq)
{
    __shared__ half_t Wh[80][68];     // folded weights, f16
    __shared__ float  Bl[80];         // folded bias
    __shared__ half_t Ob[4][32][80];  // per-wave out slab [p][o], o XOR-swizzled
    const int tid = threadIdx.x;
    for (int idx = tid; idx < 80*64; idx += 256) {
        const int o = idx >> 6, i = idx & 63;
        float sc, wv;
        if (o < 48) { sc = fg[o]*rsqrtf(fv_[o]+EPS); wv = fw[o*64+i]; }
        else { const int o2 = o-48; sc = tg[o2]*rsqrtf(tv_[o2]+EPS); wv = tw[o2*64+i]; }
        Wh[o][i] = (half_t)(wv*sc);
    }
    if (tid < 80) {
        const int o = tid;
        if (o < 48) Bl[o] = (fb_[o]-fm[o])*(fg[o]*rsqrtf(fv_[o]+EPS)) + fbe[o];
        else { const int o2 = o-48; Bl[o] = (tb_[o2]-tm[o2])*(tg[o2]*rsqrtf(tv_[o2]+EPS)) + tbe[o2]; }
    }
    __syncthreads();
    const float af = fa[0], at = ta[0];
    const int w = tid >> 6, lane = tid & 63;
    const int lmod = lane & 15, ldiv = lane >> 4;
    const int b  = blockIdx.x / 1004;
    const int nb = blockIdx.x % 1004;
    const long n0 = (long)nb*128;

    // A fragments: a[ot][ks] = Wh[16*ot + lmod][16*ks + 4*ldiv .. +3]
    half4 a[5][4];
    #pragma unroll
    for (int ot = 0; ot < 5; ++ot)
        #pragma unroll
        for (int ks = 0; ks < 4; ++ks)
            a[ot][ks] = *(const half4*)&Wh[16*ot + lmod][16*ks + 4*ldiv];
    f32x4 bias[5];
    #pragma unroll
    for (int ot = 0; ot < 5; ++ot)
        #pragma unroll
        for (int r = 0; r < 4; ++r)
            bias[ot][r] = Bl[16*ot + 4*ldiv + r];

    const float* xplane = x + (long)b*CIN*FT;
    // B fragments for BOTH position sub-tiles issued up-front (more MLP).
    half4 bfr[2][4];
    #pragma unroll
    for (int pt = 0; pt < 2; ++pt) {
        const long p = n0 + 32*w + 16*pt + lmod;
        const long pc = (p < FT) ? p : (FT-1);   // clamp; value unused when OOB
        const float* xp = xplane + pc;
        #pragma unroll
        for (int ks = 0; ks < 4; ++ks) {
            #pragma unroll
            for (int e = 0; e < 4; ++e) {
                const int ch = 16*ks + 4*ldiv + e;
                bfr[pt][ks][e] = (half_t)xp[(long)ch*FT];
            }
        }
    }
    #pragma unroll
    for (int pt = 0; pt < 2; ++pt) {
        const int pl = 16*pt + lmod;
        const int msk = ((pl >> 2) & 3) << 2;    // bits 2-3: stays in 16-group
        #pragma unroll
        for (int ot = 0; ot < 5; ++ot) {
            f32x4 acc = bias[ot];
            #pragma unroll
            for (int ks = 0; ks < 4; ++ks)
                acc = __builtin_amdgcn_mfma_f32_16x16x16f16(a[ot][ks], bfr[pt][ks], acc, 0, 0, 0);
            const float alpha = (ot < 3) ? af : at;
            half4 hv;
            #pragma unroll
            for (int r = 0; r < 4; ++r) {
                float v = acc[r];
                v = v >= 0.f ? v : alpha*v;
                hv[r] = (half_t)v;
            }
            // element o=16ot+4ldiv+r lands at col o^msk (msk has no bits 0-1)
            *(half4*)&Ob[w][pl][(16*ot + 4*ldiv) ^ msk] = hv;
        }
    }
    // Store phase: wave-local (no barrier needed; same-wave LDS ordering).
    const int pr = lane & 7, og0 = lane >> 3;
    const long pbase = n0 + 32*w + 4*pr;
    if (pbase < FT) {    // FT%4==0: half4 chunks are all-or-nothing valid
        const int msk = (pr & 3) << 2;           // row 4*pr+e -> (p>>2)&3 == pr&3
        #pragma unroll
        for (int i = 0; i < 10; ++i) {
            const int o = og0 + 8*i;
            half4 hv;
            #pragma unroll
            for (int e = 0; e < 4; ++e) hv[e] = Ob[w][4*pr + e][o ^ msk];
            half_t* dst = (o < 48) ? (fq + ((long)b*48 + o)*FT + pbase)
                                   : (tq + ((long)b*32 + (o-48))*FT + pbase);
            *(half4*)dst = hv;
        }
    }
}

// ---------------------------------------------------------------------------
// Transpose (f16->f16): src[plane][R][CS(row stride)] logical [R][C] ->
// dst[plane][C][RP], pad r in [R,RP) zeroed. 64x64 tile; half4 (8B/lane)
// global access on BOTH sides.
// ---------------------------------------------------------------------------
__global__ __launch_bounds__(256) void transpose_h2h_kernel(
    const half_t* __restrict__ src, half_t* __restrict__ dst,
    int R, int C, int CS, int RP)
{
    __shared__ half_t tile[64][68];
    const int plane = blockIdx.x;
    const int rb = blockIdx.y*64, cb = blockIdx.z*64;
    const half_t* s = src + (long)plane*R*CS;
    half_t* d = dst + (long)plane*C*RP;
    const int q4 = (threadIdx.x & 15)*4;   // 0..60
    const int wl = threadIdx.x >> 4;       // 0..15
    #pragma unroll
    for (int p = 0; p < 4; ++p) {
        const int r = rb + wl + 16*p;
        const int c = cb + q4;
        half4 v = {(half_t)0.f,(half_t)0.f,(half_t)0.f,(half_t)0.f};
        if (r < R) {
            const half_t* srow = s + (long)r*CS;
            if (c + 3 < C) v = *(const half4*)(srow + c);
            else {
                #pragma unroll
                for (int e = 0; e < 4; ++e) if (c+e < C) v[e] = srow[c+e];
            }
        }
        *(half4*)&tile[wl + 16*p][q4] = v;
    }
    __syncthreads();
    #pragma unroll
    for (int p = 0; p < 4; ++p) {
        const int c = cb + wl + 16*p;
        if (c >= C) continue;
        const int r0 = rb + q4;
        half4 o;
        #pragma unroll
        for (int e = 0; e < 4; ++e) o[e] = tile[q4 + e][wl + 16*p];
        half_t* drow = d + (long)c*RP;
        if (r0 + 3 < RP) *(half4*)(drow + r0) = o;
        else {
            #pragma unroll
            for (int e = 0; e < 4; ++e) if (r0+e < RP) drow[r0+e] = o[e];
        }
    }
}

// ---------------------------------------------------------------------------
// Stage 2: frequency attention, MFMA flash-style. One block per (b,t),
// 512 threads (8 waves). Paired K-tiles per softmax update; exp2 with
// log2e folded into Q scale. Output f16 into padded [t][f pad 260] rows.
// ---------------------------------------------------------------------------
__global__ __launch_bounds__(512) void fattn_kernel(
    const half_t* __restrict__ fqT, half_t* __restrict__ foT)
{
    __shared__ half_t KT[272*20];   // [y][c]
    __shared__ half_t QT[272*20];   // [f][c], pre-scaled by 0.25*log2e
    __shared__ half_t Vs[16*280];   // [c][y]
    const int tid = threadIdx.x;
    const int b = blockIdx.x / TD, t = blockIdx.x % TD;
    const half_t* base = fqT + (long)b*48*FQT_PLANE + (long)t*FDP;
    const half_t qsc = (half_t)(0.25f*LOG2E);
    for (int s = tid; s < 48*68; s += 512) {
        const int c3 = s / 68, j = s - c3*68;
        const int f0 = 4*j;
        half4 v = {(half_t)0.f,(half_t)0.f,(half_t)0.f,(half_t)0.f};
        if (f0 < FDP) v = *(const half4*)(base + (long)c3*FQT_PLANE + f0);
        const int c = c3 / 3, wh = c3 - 3*c;   // q=3c, k=3c+1, v=3c+2
        if (wh == 0) {
            #pragma unroll
            for (int e = 0; e < 4; ++e) QT[(f0+e)*20 + c] = v[e]*qsc;
        } else if (wh == 1) {
            #pragma unroll
            for (int e = 0; e < 4; ++e) KT[(f0+e)*20 + c] = v[e];
        } else {
            *(half4*)&Vs[c*280 + f0] = v;
        }
    }
    __syncthreads();
    const int w = tid >> 6, lane = tid & 63;
    const int lmod = lane & 15, ldiv = lane >> 4;
    for (int ft = w; ft < 17; ft += 8) {    // w=0: {0,8,16}; others {w, w+8}
        const int f0 = 16*ft;
        const half4 qb = *(const half4*)&QT[(f0+lmod)*20 + 4*ldiv];
        f32x4 o = {0.f,0.f,0.f,0.f};
        float m = NEGINF, l = 0.f;
        // 8 pairs of full tiles: y = 0..255, all < FD
        for (int yt = 0; yt < 16; yt += 2) {
            const int y0 = 16*yt;
            const half4 ka0 = *(const half4*)&KT[(y0   +lmod)*20 + 4*ldiv];
            const half4 ka1 = *(const half4*)&KT[(y0+16+lmod)*20 + 4*ldiv];
            f32x4 s0 = __builtin_amdgcn_mfma_f32_16x16x16f16(
                ka0, qb, (f32x4){0.f,0.f,0.f,0.f}, 0, 0, 0);
            f32x4 s1 = __builtin_amdgcn_mfma_f32_16x16x16f16(
                ka1, qb, (f32x4){0.f,0.f,0.f,0.f}, 0, 0, 0);
            float mt = fmaxf(fmaxf(fmaxf(s0[0],s0[1]), fmaxf(s0[2],s0[3])),
                             fmaxf(fmaxf(s1[0],s1[1]), fmaxf(s1[2],s1[3])));
            mt = fmaxf(mt, __shfl_xor(mt, 16, 64));
            mt = fmaxf(mt, __shfl_xor(mt, 32, 64));
            const float mn = fmaxf(m, mt);
            const float alpha = EXP2F(m - mn);
            half4 pb0, pb1; float ps = 0.f;
            #pragma unroll
            for (int r = 0; r < 4; ++r) {
                const float p0 = EXP2F(s0[r] - mn);
                const float p1 = EXP2F(s1[r] - mn);
                pb0[r] = (half_t)p0; pb1[r] = (half_t)p1;
                ps += p0 + p1;
            }
            ps += __shfl_xor(ps, 16, 64);
            ps += __shfl_xor(ps, 32, 64);
            l = l*alpha + ps;  m = mn;
            o[0] *= alpha; o[1] *= alpha; o[2] *= alpha; o[3] *= alpha;
            const half4 va0 = *(const half4*)&Vs[lmod*280 + y0      + 4*ldiv];
            const half4 va1 = *(const half4*)&Vs[lmod*280 + y0 + 16 + 4*ldiv];
            o = __builtin_amdgcn_mfma_f32_16x16x16f16(va0, pb0, o, 0, 0, 0);
            o = __builtin_amdgcn_mfma_f32_16x16x16f16(va1, pb1, o, 0, 0, 0);
        }
        {   // tail tile yt=16: y = 256..271, mask y >= FD
            const int y0 = 256;
            const half4 ka = *(const half4*)&KT[(y0+lmod)*20 + 4*ldiv];
            f32x4 s = __builtin_amdgcn_mfma_f32_16x16x16f16(
                ka, qb, (f32x4){0.f,0.f,0.f,0.f}, 0, 0, 0);
            #pragma unroll
            for (int r = 0; r < 4; ++r)
                if (y0 + 4*ldiv + r >= FD) s[r] = NEGINF;
            float mt = fmaxf(fmaxf(s[0],s[1]), fmaxf(s[2],s[3]));
            mt = fmaxf(mt, __shfl_xor(mt, 16, 64));
            mt = fmaxf(mt, __shfl_xor(mt, 32, 64));
            const float mn = fmaxf(m, mt);
            const float alpha = EXP2F(m - mn);
            half4 pb; float ps = 0.f;
            #pragma unroll
            for (int r = 0; r < 4; ++r) {
                const float p = EXP2F(s[r] - mn);
                pb[r] = (half_t)p; ps += p;
            }
            ps += __shfl_xor(ps, 16, 64);
            ps += __shfl_xor(ps, 32, 64);
            l = l*alpha + ps;  m = mn;
            o[0] *= alpha; o[1] *= alpha; o[2] *= alpha; o[3] *= alpha;
            const half4 va = *(const half4*)&Vs[lmod*280 + y0 + 4*ldiv];
            o = __builtin_amdgcn_mfma_f32_16x16x16f16(va, pb, o, 0, 0, 0);
        }
        const float inv = 1.f/l;
        const int f = f0 + lmod;
        if (f < FD) {
            #pragma unroll
            for (int r = 0; r < 4; ++r) {
                const int c = 4*ldiv + r;
                foT[((long)(b*16 + c)*TD + t)*FDP + f] = (half_t)(o[r]*inv);
            }
        }
    }
}

// ---------------------------------------------------------------------------
// Stage 3: causal time attention. Round-9 restructure: grid (BB*FD, 2) —
// blockIdx.y=0 handles Q-tiles 0..15 (stages K/FO rows 0..255 only),
// y=1 handles Q-tiles 16..31 (stages all 500). Q lives in REGISTERS
// (2 half4/lane), QT removed from LDS: 57.6 -> 37.1 KB, grid 514 -> 1028
// blocks -> wave residency ~50% -> ~100% for this latency-bound kernel.
// ---------------------------------------------------------------------------
__global__ __launch_bounds__(512) void tattn_kernel(
    const half_t* __restrict__ tq, const half_t* __restrict__ fo,
    float* __restrict__ tout)
{
    extern __shared__ half_t lds[];
    half_t* KT  = lds;              // [512 y][20]
    half_t* FOs = KT + 512*20;      // [16 c][520]
    const int tid = threadIdx.x;
    const int b = blockIdx.x / FD, f = blockIdx.x % FD;
    const int h = blockIdx.y;       // 0: Q-tiles 0..15; 1: Q-tiles 16..31
    const half_t* qbase = tq + (long)b*32*FT + (long)f*TD;
    const half_t* fbase = fo + (long)b*16*FT + (long)f*TD;
    const half_t qsc = (half_t)(0.25f*LOG2E);
    // Stage K (odd channels) and FO; h=0 needs only y < 256.
    const int shift = h ? 7 : 6;            // quads per channel: 128 or 64
    const int nq = 16 << shift;
    for (int idx = tid; idx < nq; idx += 512) {
        const int c = idx >> shift;
        const int y4 = (idx & ((1 << shift) - 1)) * 4;
        half4 kv = {(half_t)0.f,(half_t)0.f,(half_t)0.f,(half_t)0.f};
        half4 fv = kv;
        if (y4 + 3 < TD) {   // TD%4==0: quads all-or-nothing valid
            kv = *(const half4*)(qbase + (long)(2*c+1)*FT + y4);
            fv = *(const half4*)(fbase + (long)c*FT + y4);
        }
        #pragma unroll
        for (int e = 0; e < 4; ++e) KT[(y4+e)*20 + c] = kv[e];
        *(half4*)&FOs[c*520 + y4] = fv;
    }
    const int w = tid >> 6, lane = tid & 63;
    const int lmod = lane & 15, ldiv = lane >> 4;
    const int tts[2] = { h ? (16 + w) : w, h ? (31 - w) : (15 - w) };
    // Q fragments in registers (global scalar loads; tq is L2/L3-hot).
    half4 qbr[2];
    #pragma unroll
    for (int i = 0; i < 2; ++i) {
        const int t = 16*tts[i] + lmod;
        #pragma unroll
        for (int e = 0; e < 4; ++e) {
            const int c = 4*ldiv + e;
            half_t qv = (half_t)0.f;
            if (t < TD) qv = qbase[(long)(2*c)*FT + t];
            qbr[i][e] = qv * qsc;
        }
    }
    __syncthreads();
    #pragma unroll
    for (int i = 0; i < 2; ++i) {
        const int tt = tts[i];
        const int t0 = 16*tt;
        const half4 qb = qbr[i];
        f32x4 o = {0.f,0.f,0.f,0.f};
        float m = NEGINF, l = 0.f;
        int yt = 0;
        // pairs of strictly-below-diagonal (unmasked) tiles
        for (; yt + 1 < tt; yt += 2) {
            const int y0 = 16*yt;
            const half4 ka0 = *(const half4*)&KT[(y0   +lmod)*20 + 4*ldiv];
            const half4 ka1 = *(const half4*)&KT[(y0+16+lmod)*20 + 4*ldiv];
            f32x4 s0 = __builtin_amdgcn_mfma_f32_16x16x16f16(
                ka0, qb, (f32x4){0.f,0.f,0.f,0.f}, 0, 0, 0);
            f32x4 s1 = __builtin_amdgcn_mfma_f32_16x16x16f16(
                ka1, qb, (f32x4){0.f,0.f,0.f,0.f}, 0, 0, 0);
            float mt = fmaxf(fmaxf(fmaxf(s0[0],s0[1]), fmaxf(s0[2],s0[3])),
                             fmaxf(fmaxf(s1[0],s1[1]), fmaxf(s1[2],s1[3])));
            mt = fmaxf(mt, __shfl_xor(mt, 16, 64));
            mt = fmaxf(mt, __shfl_xor(mt, 32, 64));
            const float mn = fmaxf(m, mt);
            const float alpha = EXP2F(m - mn);
            half4 pb0, pb1; float ps = 0.f;
            #pragma unroll
            for (int r = 0; r < 4; ++r) {
                const float p0 = EXP2F(s0[r] - mn);
                const float p1 = EXP2F(s1[r] - mn);
                pb0[r] = (half_t)p0; pb1[r] = (half_t)p1;
                ps += p0 + p1;
            }
            ps += __shfl_xor(ps, 16, 64);
            ps += __shfl_xor(ps, 32, 64);
            l = l*alpha + ps;  m = mn;
            o[0] *= alpha; o[1] *= alpha; o[2] *= alpha; o[3] *= alpha;
            const half4 fa0 = *(const half4*)&FOs[lmod*520 + y0      + 4*ldiv];
            const half4 fa1 = *(const half4*)&FOs[lmod*520 + y0 + 16 + 4*ldiv];
            o = __builtin_amdgcn_mfma_f32_16x16x16f16(fa0, pb0, o, 0, 0, 0);
            o = __builtin_amdgcn_mfma_f32_16x16x16f16(fa1, pb1, o, 0, 0, 0);
        }
        if (yt < tt) {
            // tail pair: full tile yt, diagonal tile yt+1 == tt (masked)
            const int y0 = 16*yt;
            const half4 ka0 = *(const half4*)&KT[(y0   +lmod)*20 + 4*ldiv];
            const half4 ka1 = *(const half4*)&KT[(y0+16+lmod)*20 + 4*ldiv];
            f32x4 s0 = __builtin_amdgcn_mfma_f32_16x16x16f16(
                ka0, qb, (f32x4){0.f,0.f,0.f,0.f}, 0, 0, 0);
            f32x4 s1 = __builtin_amdgcn_mfma_f32_16x16x16f16(
                ka1, qb, (f32x4){0.f,0.f,0.f,0.f}, 0, 0, 0);
            #pragma unroll
            for (int r = 0; r < 4; ++r)
                if (4*ldiv + r > lmod) s1[r] = NEGINF;
            float mt = fmaxf(fmaxf(fmaxf(s0[0],s0[1]), fmaxf(s0[2],s0[3])),
                             fmaxf(fmaxf(s1[0],s1[1]), fmaxf(s1[2],s1[3])));
            mt = fmaxf(mt, __shfl_xor(mt, 16, 64));
            mt = fmaxf(mt, __shfl_xor(mt, 32, 64));
            const float mn = fmaxf(m, mt);
            const float alpha = EXP2F(m - mn);
            half4 pb0, pb1; float ps = 0.f;
            #pragma unroll
            for (int r = 0; r < 4; ++r) {
                const float p0 = EXP2F(s0[r] - mn);
                const float p1 = EXP2F(s1[r] - mn);
                pb0[r] = (half_t)p0; pb1[r] = (half_t)p1;
                ps += p0 + p1;
            }
            ps += __shfl_xor(ps, 16, 64);
            ps += __shfl_xor(ps, 32, 64);
            l = l*alpha + ps;  m = mn;
            o[0] *= alpha; o[1] *= alpha; o[2] *= alpha; o[3] *= alpha;
            const half4 fa0 = *(const half4*)&FOs[lmod*520 + y0      + 4*ldiv];
            const half4 fa1 = *(const half4*)&FOs[lmod*520 + y0 + 16 + 4*ldiv];
            o = __builtin_amdgcn_mfma_f32_16x16x16f16(fa0, pb0, o, 0, 0, 0);
            o = __builtin_amdgcn_mfma_f32_16x16x16f16(fa1, pb1, o, 0, 0, 0);
        } else {
            // single diagonal tile yt == tt (masked)
            const int y0 = 16*tt;
            const half4 ka = *(const half4*)&KT[(y0+lmod)*20 + 4*ldiv];
            f32x4 s = __builtin_amdgcn_mfma_f32_16x16x16f16(
                ka, qb, (f32x4){0.f,0.f,0.f,0.f}, 0, 0, 0);
            #pragma unroll
            for (int r = 0; r < 4; ++r)
                if (4*ldiv + r > lmod) s[r] = NEGINF;
            float mt = fmaxf(fmaxf(s[0],s[1]), fmaxf(s[2],s[3]));
            mt = fmaxf(mt, __shfl_xor(mt, 16, 64));
            mt = fmaxf(mt, __shfl_xor(mt, 32, 64));
            const float mn = fmaxf(m, mt);
            const float alpha = EXP2F(m - mn);
            half4 pb; float ps = 0.f;
            #pragma unroll
            for (int r = 0; r < 4; ++r) {
                const float p = EXP2F(s[r] - mn);
                pb[r] = (half_t)p; ps += p;
            }
            ps += __shfl_xor(ps, 16, 64);
            ps += __shfl_xor(ps, 32, 64);
            l = l*alpha + ps;  m = mn;
            o[0] *= alpha; o[1] *= alpha; o[2] *= alpha; o[3] *= alpha;
            const half4 fa4 = *(const half4*)&FOs[lmod*520 + y0 + 4*ldiv];
            o = __builtin_amdgcn_mfma_f32_16x16x16f16(fa4, pb, o, 0, 0, 0);
        }
        const float inv = 1.f/l;
        const int t = t0 + lmod;
        if (t < TD) {
            #pragma unroll
            for (int r = 0; r < 4; ++r) {
                const int c = 4*ldiv + r;
                tout[((long)(b*16 + c)*FD + f)*TD + t] = o[r]*inv;
            }
        }
    }
}

// ---------------------------------------------------------------------------
// Stage 4: proj 16->64 + BN + PReLU + residual. cg-split, float4 streams.
// ---------------------------------------------------------------------------
__global__ __launch_bounds__(256) void proj_kernel(
    const float* __restrict__ tout, const float* __restrict__ x,
    const float* __restrict__ pw, const float* __restrict__ pb_,
    const float* __restrict__ pg, const float* __restrict__ pbe,
    const float* __restrict__ pm, const float* __restrict__ pv_,
    const float* __restrict__ pa,
    float* __restrict__ out)
{
    __shared__ float PW[32*16];
    __shared__ float PB[32];
    const int tid = threadIdx.x;
    const int cg   = blockIdx.x & 1;
    const int bidx = blockIdx.x >> 1;
    const int ob   = cg*32;
    for (int idx = tid; idx < 32*16; idx += 256) {
        const int ol = idx >> 4;
        const int o = ob + ol;
        PW[idx] = pw[o*16 + (idx & 15)]*(pg[o]*rsqrtf(pv_[o]+EPS));
    }
    if (tid < 32) {
        const int o = ob + tid;
        PB[tid] = (pb_[o]-pm[o])*(pg[o]*rsqrtf(pv_[o]+EPS)) + pbe[o];
    }
    __syncthreads();
    const float ap = pa[0];
    const int og = tid >> 6, lane = tid & 63;   // og 0..3: outputs ob+og*8 .. +8
    const int b  = bidx / 502;
    const int nb = bidx % 502;
    const long n0 = (long)nb*256 + lane*4;
    if (n0 >= FT) return;
    float4 acc[8];
    #pragma unroll
    for (int j = 0; j < 8; ++j) {
        const float bv = PB[og*8+j];
        acc[j] = make_float4(bv, bv, bv, bv);
    }
    const float* tb = tout + (long)b*16*FT + n0;
    for (int cc = 0; cc < 16; cc += 4) {
        const float* tc = tb + (long)cc*FT;
        const float4 t0 = *(const float4*)(tc);
        const float4 t1 = *(const float4*)(tc + FT);
        const float4 t2 = *(const float4*)(tc + 2*FT);
        const float4 t3 = *(const float4*)(tc + 3*FT);
        #pragma unroll
        for (int j = 0; j < 8; ++j) {
            const float4 wv = *(const float4*)&PW[(og*8+j)*16 + cc];
            acc[j].x += wv.x*t0.x + wv.y*t1.x + wv.z*t2.x + wv.w*t3.x;
            acc[j].y += wv.x*t0.y + wv.y*t1.y + wv.z*t2.y + wv.w*t3.y;
            acc[j].z += wv.x*t0.z + wv.y*t1.z + wv.z*t2.z + wv.w*t3.z;
            acc[j].w += wv.x*t0.w + wv.y*t1.w + wv.z*t2.w + wv.w*t3.w;
        }
    }
    #pragma unroll
    for (int j = 0; j < 8; ++j) {
        const int o = ob + og*8 + j;
        float4 v = acc[j];
        v.x = v.x >= 0.f ? v.x : ap*v.x;
        v.y = v.y >= 0.f ? v.y : ap*v.y;
        v.z = v.z >= 0.f ? v.z : ap*v.z;
        v.w = v.w >= 0.f ? v.w : ap*v.w;
        const long gi = (long)(b*64 + o)*FT + n0;
        const float4 xv = *(const float4*)(x + gi);
        v.x += xv.x; v.y += xv.y; v.z += xv.z; v.w += xv.w;
        *(float4*)(out + gi) = v;
    }
}

extern "C" void kernel_launch(void* const* d_in, const int* in_sizes, int n_in,
                              void* d_out, int out_size, void* d_ws, size_t ws_size,
                              hipStream_t stream)
{
    const float* x     = (const float*)d_in[0];
    const float* fw    = (const float*)d_in[1];
    const float* fb_   = (const float*)d_in[2];
    const float* fg    = (const float*)d_in[3];
    const float* fbe   = (const float*)d_in[4];
    const float* fm    = (const float*)d_in[5];
    const float* fv_   = (const float*)d_in[6];
    const float* fa    = (const float*)d_in[7];
    const float* tw    = (const float*)d_in[8];
    const float* tb_   = (const float*)d_in[9];
    const float* tg    = (const float*)d_in[10];
    const float* tbe   = (const float*)d_in[11];
    const float* tm    = (const float*)d_in[12];
    const float* tv_   = (const float*)d_in[13];
    const float* ta    = (const float*)d_in[14];
    const float* pw    = (const float*)d_in[15];
    const float* pb_   = (const float*)d_in[16];
    const float* pg    = (const float*)d_in[17];
    const float* pbe   = (const float*)d_in[18];
    const float* pm    = (const float*)d_in[19];
    const float* pv_   = (const float*)d_in[20];
    const float* pa    = (const float*)d_in[21];
    float* out = (float*)d_out;

    // Workspace layout (bytes):
    //  A: fqh  f16 [2][48][FT]           24,672,000   (foTh f16 [2][16][TD][260]=8,320,000 aliases after T1)
    //  B: foh  f16 [2][16][FT]            8,224,000
    //  C: tqh  f16 [2][32][FT]           16,448,000
    //  D: fqTh f16 [96][FQT_PLANE]       24,960,000   (tout f32 [2][16][FT] aliases after fattn)
    char* base = (char*)d_ws;
    const size_t szA = (size_t)BB*48*FT*sizeof(half_t);
    const size_t szB = (size_t)BB*16*FT*sizeof(half_t);
    const size_t szC = (size_t)BB*32*FT*sizeof(half_t);
    const size_t szD = (size_t)96*FQT_PLANE*sizeof(half_t);
    const size_t need = szA + szB + szC + szD;   // 74,304,000
    if (ws_size < need) return;
    half_t* fqh  = (half_t*)base;
    half_t* foTh = (half_t*)base;                // alias A (8.32 MB < szA)
    half_t* foh  = (half_t*)(base + szA);
    half_t* tqh  = (half_t*)(base + szA + szB);
    half_t* fqTh = (half_t*)(base + szA + szB + szC);
    float*  tout = (float*)(base + szA + szB + szC);  // alias D

    stage1_kernel<<<dim3(BB*1004), dim3(256), 0, stream>>>(
        x, fw, fb_, fg, fbe, fm, fv_, fa, tw, tb_, tg, tbe, tm, tv_, ta, fqh, tqh);

    // T1: fq[b][c][f][t] -> fqT[b][c][t][f(pad 260)]
    transpose_h2h_kernel<<<dim3(BB*48, 5, 8), dim3(256), 0, stream>>>(
        fqh, fqTh, FD, TD, TD, FDP);

    fattn_kernel<<<dim3(BB*TD), dim3(512), 0, stream>>>(fqTh, foTh);

    // T2: foT[b][c][t][f(pad 260)] (f16) -> fo[b][c][f][t] (f16)
    transpose_h2h_kernel<<<dim3(BB*16, 8, 5), dim3(256), 0, stream>>>(
        foTh, foh, TD, FD, FDP, TD);

    const int tlds = (512*20 + 16*520)*(int)sizeof(half_t);  // 37,120 B
    (void)hipFuncSetAttribute(reinterpret_cast<const void*>(tattn_kernel),
                        hipFuncAttributeMaxDynamicSharedMemorySize, tlds);
    tattn_kernel<<<dim3(BB*FD, 2), dim3(512), tlds, stream>>>(tqh, foh, tout);

    proj_kernel<<<dim3(BB*502*2), dim3(256), 0, stream>>>(
        tout, x, pw, pb_, pg, pbe, pm, pv_, pa, out);
}

// Round 11
// 263.593 us; speedup vs baseline: 1.1111x; 1.0666x over previous
//
#include <hip/hip_runtime.h>

#define BB 2
#define CIN 64
#define FD 257
#define TD 500
#define FT (FD*TD)      // 128500
#define EPS 1e-5f
#define NEGINF (-3.0e38f)
#define FDP 260         // padded row length (halves, 8B-aligned rows)
#define FQT_PLANE (TD*FDP)   // 130000 halves per (b,channel) plane
#define LOG2E 1.44269504088896f
#define EXP2F(x) __builtin_amdgcn_exp2f(x)

typedef _Float16 half_t;
typedef half_t half2_t __attribute__((ext_vector_type(2)));
typedef half_t half4 __attribute__((ext_vector_type(4)));
typedef float  f32x4 __attribute__((ext_vector_type(4)));

// ---------------------------------------------------------------------------
// Stage 1 (MFMA): out[80, FT] = W[80,64] . x[64, FT], fused BN fold + PReLU.
// Round-6 form (best measured: ~52us).
// ---------------------------------------------------------------------------
__global__ __launch_bounds__(256) void stage1_kernel(
    const float* __restrict__ x,
    const float* __restrict__ fw, const float* __restrict__ fb_,
    const float* __restrict__ fg, const float* __restrict__ fbe,
    const float* __restrict__ fm, const float* __restrict__ fv_,
    const float* __restrict__ fa,
    const float* __restrict__ tw, const float* __restrict__ tb_,
    const float* __restrict__ tg, const float* __restrict__ tbe,
    const float* __restrict__ tm, const float* __restrict__ tv_,
    const float* __restrict__ ta,
    half_t* __restrict__ fq, half_t* __restrict__ tq)
{
    __shared__ half_t Wh[80][68];     // folded weights, f16
    __shared__ float  Bl[80];         // folded bias
    __shared__ half_t Ob[4][32][80];  // per-wave out slab [p][o], o XOR-swizzled
    const int tid = threadIdx.x;
    for (int idx = tid; idx < 80*64; idx += 256) {
        const int o = idx >> 6, i = idx & 63;
        float sc, wv;
        if (o < 48) { sc = fg[o]*rsqrtf(fv_[o]+EPS); wv = fw[o*64+i]; }
        else { const int o2 = o-48; sc = tg[o2]*rsqrtf(tv_[o2]+EPS); wv = tw[o2*64+i]; }
        Wh[o][i] = (half_t)(wv*sc);
    }
    if (tid < 80) {
        const int o = tid;
        if (o < 48) Bl[o] = (fb_[o]-fm[o])*(fg[o]*rsqrtf(fv_[o]+EPS)) + fbe[o];
        else { const int o2 = o-48; Bl[o] = (tb_[o2]-tm[o2])*(tg[o2]*rsqrtf(tv_[o2]+EPS)) + tbe[o2]; }
    }
    __syncthreads();
    const float af = fa[0], at = ta[0];
    const int w = tid >> 6, lane = tid & 63;
    const int lmod = lane & 15, ldiv = lane >> 4;
    const int b  = blockIdx.x / 1004;
    const int nb = blockIdx.x % 1004;
    const long n0 = (long)nb*128;

    half4 a[5][4];
    #pragma unroll
    for (int ot = 0; ot < 5; ++ot)
        #pragma unroll
        for (int ks = 0; ks < 4; ++ks)
            a[ot][ks] = *(const half4*)&Wh[16*ot + lmod][16*ks + 4*ldiv];
    f32x4 bias[5];
    #pragma unroll
    for (int ot = 0; ot < 5; ++ot)
        #pragma unroll
        for (int r = 0; r < 4; ++r)
            bias[ot][r] = Bl[16*ot + 4*ldiv + r];

    const float* xplane = x + (long)b*CIN*FT;
    half4 bfr[2][4];
    #pragma unroll
    for (int pt = 0; pt < 2; ++pt) {
        const long p = n0 + 32*w + 16*pt + lmod;
        const long pc = (p < FT) ? p : (FT-1);   // clamp; value unused when OOB
        const float* xp = xplane + pc;
        #pragma unroll
        for (int ks = 0; ks < 4; ++ks) {
            #pragma unroll
            for (int e = 0; e < 4; ++e) {
                const int ch = 16*ks + 4*ldiv + e;
                bfr[pt][ks][e] = (half_t)xp[(long)ch*FT];
            }
        }
    }
    #pragma unroll
    for (int pt = 0; pt < 2; ++pt) {
        const int pl = 16*pt + lmod;
        const int msk = ((pl >> 2) & 3) << 2;    // bits 2-3: stays in 16-group
        #pragma unroll
        for (int ot = 0; ot < 5; ++ot) {
            f32x4 acc = bias[ot];
            #pragma unroll
            for (int ks = 0; ks < 4; ++ks)
                acc = __builtin_amdgcn_mfma_f32_16x16x16f16(a[ot][ks], bfr[pt][ks], acc, 0, 0, 0);
            const float alpha = (ot < 3) ? af : at;
            half4 hv;
            #pragma unroll
            for (int r = 0; r < 4; ++r) {
                float v = acc[r];
                v = v >= 0.f ? v : alpha*v;
                hv[r] = (half_t)v;
            }
            *(half4*)&Ob[w][pl][(16*ot + 4*ldiv) ^ msk] = hv;
        }
    }
    const int pr = lane & 7, og0 = lane >> 3;
    const long pbase = n0 + 32*w + 4*pr;
    if (pbase < FT) {    // FT%4==0: half4 chunks are all-or-nothing valid
        const int msk = (pr & 3) << 2;
        #pragma unroll
        for (int i = 0; i < 10; ++i) {
            const int o = og0 + 8*i;
            half4 hv;
            #pragma unroll
            for (int e = 0; e < 4; ++e) hv[e] = Ob[w][4*pr + e][o ^ msk];
            half_t* dst = (o < 48) ? (fq + ((long)b*48 + o)*FT + pbase)
                                   : (tq + ((long)b*32 + (o-48))*FT + pbase);
            *(half4*)dst = hv;
        }
    }
}

// ---------------------------------------------------------------------------
// Transpose (f16->f16): src[plane][R][CS(row stride)] logical [R][C] ->
// dst[plane][C][RP], pad r in [R,RP) zeroed. 64x64 tile; half4 both sides.
// ---------------------------------------------------------------------------
__global__ __launch_bounds__(256) void transpose_h2h_kernel(
    const half_t* __restrict__ src, half_t* __restrict__ dst,
    int R, int C, int CS, int RP)
{
    __shared__ half_t tile[64][68];
    const int plane = blockIdx.x;
    const int rb = blockIdx.y*64, cb = blockIdx.z*64;
    const half_t* s = src + (long)plane*R*CS;
    half_t* d = dst + (long)plane*C*RP;
    const int q4 = (threadIdx.x & 15)*4;   // 0..60
    const int wl = threadIdx.x >> 4;       // 0..15
    #pragma unroll
    for (int p = 0; p < 4; ++p) {
        const int r = rb + wl + 16*p;
        const int c = cb + q4;
        half4 v = {(half_t)0.f,(half_t)0.f,(half_t)0.f,(half_t)0.f};
        if (r < R) {
            const half_t* srow = s + (long)r*CS;
            if (c + 3 < C) v = *(const half4*)(srow + c);
            else {
                #pragma unroll
                for (int e = 0; e < 4; ++e) if (c+e < C) v[e] = srow[c+e];
            }
        }
        *(half4*)&tile[wl + 16*p][q4] = v;
    }
    __syncthreads();
    #pragma unroll
    for (int p = 0; p < 4; ++p) {
        const int c = cb + wl + 16*p;
        if (c >= C) continue;
        const int r0 = rb + q4;
        half4 o;
        #pragma unroll
        for (int e = 0; e < 4; ++e) o[e] = tile[q4 + e][wl + 16*p];
        half_t* drow = d + (long)c*RP;
        if (r0 + 3 < RP) *(half4*)(drow + r0) = o;
        else {
            #pragma unroll
            for (int e = 0; e < 4; ++e) if (r0+e < RP) drow[r0+e] = o[e];
        }
    }
}

// ---------------------------------------------------------------------------
// Stage 2: frequency attention, MFMA flash-style. One block per (b,t),
// 512 threads (8 waves). Paired K-tiles; exp2 with log2e folded into Q scale.
// Output f16 into padded [t][f pad 260] rows.
// ---------------------------------------------------------------------------
__global__ __launch_bounds__(512) void fattn_kernel(
    const half_t* __restrict__ fqT, half_t* __restrict__ foT)
{
    __shared__ half_t KT[272*20];   // [y][c]
    __shared__ half_t QT[272*20];   // [f][c], pre-scaled by 0.25*log2e
    __shared__ half_t Vs[16*280];   // [c][y]
    const int tid = threadIdx.x;
    const int b = blockIdx.x / TD, t = blockIdx.x % TD;
    const half_t* base = fqT + (long)b*48*FQT_PLANE + (long)t*FDP;
    const half_t qsc = (half_t)(0.25f*LOG2E);
    for (int s = tid; s < 48*68; s += 512) {
        const int c3 = s / 68, j = s - c3*68;
        const int f0 = 4*j;
        half4 v = {(half_t)0.f,(half_t)0.f,(half_t)0.f,(half_t)0.f};
        if (f0 < FDP) v = *(const half4*)(base + (long)c3*FQT_PLANE + f0);
        const int c = c3 / 3, wh = c3 - 3*c;   // q=3c, k=3c+1, v=3c+2
        if (wh == 0) {
            #pragma unroll
            for (int e = 0; e < 4; ++e) QT[(f0+e)*20 + c] = v[e]*qsc;
        } else if (wh == 1) {
            #pragma unroll
            for (int e = 0; e < 4; ++e) KT[(f0+e)*20 + c] = v[e];
        } else {
            *(half4*)&Vs[c*280 + f0] = v;
        }
    }
    __syncthreads();
    const int w = tid >> 6, lane = tid & 63;
    const int lmod = lane & 15, ldiv = lane >> 4;
    for (int ft = w; ft < 17; ft += 8) {    // w=0: {0,8,16}; others {w, w+8}
        const int f0 = 16*ft;
        const half4 qb = *(const half4*)&QT[(f0+lmod)*20 + 4*ldiv];
        f32x4 o = {0.f,0.f,0.f,0.f};
        float m = NEGINF, l = 0.f;
        for (int yt = 0; yt < 16; yt += 2) {
            const int y0 = 16*yt;
            const half4 ka0 = *(const half4*)&KT[(y0   +lmod)*20 + 4*ldiv];
            const half4 ka1 = *(const half4*)&KT[(y0+16+lmod)*20 + 4*ldiv];
            f32x4 s0 = __builtin_amdgcn_mfma_f32_16x16x16f16(
                ka0, qb, (f32x4){0.f,0.f,0.f,0.f}, 0, 0, 0);
            f32x4 s1 = __builtin_amdgcn_mfma_f32_16x16x16f16(
                ka1, qb, (f32x4){0.f,0.f,0.f,0.f}, 0, 0, 0);
            float mt = fmaxf(fmaxf(fmaxf(s0[0],s0[1]), fmaxf(s0[2],s0[3])),
                             fmaxf(fmaxf(s1[0],s1[1]), fmaxf(s1[2],s1[3])));
            mt = fmaxf(mt, __shfl_xor(mt, 16, 64));
            mt = fmaxf(mt, __shfl_xor(mt, 32, 64));
            const float mn = fmaxf(m, mt);
            const float alpha = EXP2F(m - mn);
            half4 pb0, pb1; float ps = 0.f;
            #pragma unroll
            for (int r = 0; r < 4; ++r) {
                const float p0 = EXP2F(s0[r] - mn);
                const float p1 = EXP2F(s1[r] - mn);
                pb0[r] = (half_t)p0; pb1[r] = (half_t)p1;
                ps += p0 + p1;
            }
            ps += __shfl_xor(ps, 16, 64);
            ps += __shfl_xor(ps, 32, 64);
            l = l*alpha + ps;  m = mn;
            o[0] *= alpha; o[1] *= alpha; o[2] *= alpha; o[3] *= alpha;
            const half4 va0 = *(const half4*)&Vs[lmod*280 + y0      + 4*ldiv];
            const half4 va1 = *(const half4*)&Vs[lmod*280 + y0 + 16 + 4*ldiv];
            o = __builtin_amdgcn_mfma_f32_16x16x16f16(va0, pb0, o, 0, 0, 0);
            o = __builtin_amdgcn_mfma_f32_16x16x16f16(va1, pb1, o, 0, 0, 0);
        }
        {   // tail tile yt=16: y = 256..271, mask y >= FD
            const int y0 = 256;
            const half4 ka = *(const half4*)&KT[(y0+lmod)*20 + 4*ldiv];
            f32x4 s = __builtin_amdgcn_mfma_f32_16x16x16f16(
                ka, qb, (f32x4){0.f,0.f,0.f,0.f}, 0, 0, 0);
            #pragma unroll
            for (int r = 0; r < 4; ++r)
                if (y0 + 4*ldiv + r >= FD) s[r] = NEGINF;
            float mt = fmaxf(fmaxf(s[0],s[1]), fmaxf(s[2],s[3]));
            mt = fmaxf(mt, __shfl_xor(mt, 16, 64));
            mt = fmaxf(mt, __shfl_xor(mt, 32, 64));
            const float mn = fmaxf(m, mt);
            const float alpha = EXP2F(m - mn);
            half4 pb; float ps = 0.f;
            #pragma unroll
            for (int r = 0; r < 4; ++r) {
                const float p = EXP2F(s[r] - mn);
                pb[r] = (half_t)p; ps += p;
            }
            ps += __shfl_xor(ps, 16, 64);
            ps += __shfl_xor(ps, 32, 64);
            l = l*alpha + ps;  m = mn;
            o[0] *= alpha; o[1] *= alpha; o[2] *= alpha; o[3] *= alpha;
            const half4 va = *(const half4*)&Vs[lmod*280 + y0 + 4*ldiv];
            o = __builtin_amdgcn_mfma_f32_16x16x16f16(va, pb, o, 0, 0, 0);
        }
        const float inv = 1.f/l;
        const int f = f0 + lmod;
        if (f < FD) {
            #pragma unroll
            for (int r = 0; r < 4; ++r) {
                const int c = 4*ldiv + r;
                foT[((long)(b*16 + c)*TD + t)*FDP + f] = (half_t)(o[r]*inv);
            }
        }
    }
}

// ---------------------------------------------------------------------------
// Stage 3+4 FUSED: causal time attention + proj + residual. Grid (BB*FD, 2).
// tattn's accumulator o[r] = tout[c=4*ldiv+r][t=t0+lmod] is EXACTLY the
// B-fragment layout for proj's 64x16 MFMA (A = folded pw^T), so proj runs
// in the epilogue: 4 MFMAs + PReLU + residual x + direct f32 out store.
// Eliminates the tout round-trip (~98 MB) and the proj kernel.
// ---------------------------------------------------------------------------
__global__ __launch_bounds__(512) void tattn_kernel(
    const half_t* __restrict__ tq, const half_t* __restrict__ fo,
    const float* __restrict__ pw, const float* __restrict__ pb_,
    const float* __restrict__ pg, const float* __restrict__ pbe,
    const float* __restrict__ pm, const float* __restrict__ pv_,
    const float* __restrict__ pal,
    const float* __restrict__ x, float* __restrict__ out)
{
    extern __shared__ half_t lds[];
    half_t* KT  = lds;              // [512 y][20]
    half_t* FOs = KT + 512*20;      // [16 c][520]
    half_t* PWh = FOs + 16*520;     // [64 o][20] folded proj weights (f16)
    float*  PBl = (float*)(PWh + 64*20);  // [64] folded proj bias
    const int tid = threadIdx.x;
    const int b = blockIdx.x / FD, f = blockIdx.x % FD;
    const int h = blockIdx.y;       // 0: Q-tiles 0..15; 1: Q-tiles 16..31
    const half_t* qbase = tq + (long)b*32*FT + (long)f*TD;
    const half_t* fbase = fo + (long)b*16*FT + (long)f*TD;
    const half_t qsc = (half_t)(0.25f*LOG2E);
    // Fold proj weights/bias into LDS.
    if (tid < 64) {
        const int o64 = tid;
        const float sc = pg[o64]*rsqrtf(pv_[o64]+EPS);
        PBl[o64] = (pb_[o64]-pm[o64])*sc + pbe[o64];
        #pragma unroll
        for (int c = 0; c < 16; ++c)
            PWh[o64*20 + c] = (half_t)(pw[o64*16 + c]*sc);
    }
    // Stage K (odd channels) and FO; h=0 needs only y < 256.
    const int shift = h ? 7 : 6;            // quads per channel: 128 or 64
    const int nq = 16 << shift;
    for (int idx = tid; idx < nq; idx += 512) {
        const int c = idx >> shift;
        const int y4 = (idx & ((1 << shift) - 1)) * 4;
        half4 kv = {(half_t)0.f,(half_t)0.f,(half_t)0.f,(half_t)0.f};
        half4 fv = kv;
        if (y4 + 3 < TD) {   // TD%4==0: quads all-or-nothing valid
            kv = *(const half4*)(qbase + (long)(2*c+1)*FT + y4);
            fv = *(const half4*)(fbase + (long)c*FT + y4);
        }
        #pragma unroll
        for (int e = 0; e < 4; ++e) KT[(y4+e)*20 + c] = kv[e];
        *(half4*)&FOs[c*520 + y4] = fv;
    }
    const int w = tid >> 6, lane = tid & 63;
    const int lmod = lane & 15, ldiv = lane >> 4;
    const int tts[2] = { h ? (16 + w) : w, h ? (31 - w) : (15 - w) };
    // Q fragments in registers (global scalar loads; tq is L2/L3-hot).
    half4 qbr[2];
    #pragma unroll
    for (int i = 0; i < 2; ++i) {
        const int t = 16*tts[i] + lmod;
        #pragma unroll
        for (int e = 0; e < 4; ++e) {
            const int c = 4*ldiv + e;
            half_t qv = (half_t)0.f;
            if (t < TD) qv = qbase[(long)(2*c)*FT + t];
            qbr[i][e] = qv * qsc;
        }
    }
    const float app = pal[0];
    __syncthreads();
    #pragma unroll
    for (int i = 0; i < 2; ++i) {
        const int tt = tts[i];
        const int t0 = 16*tt;
        const half4 qb = qbr[i];
        f32x4 o = {0.f,0.f,0.f,0.f};
        float m = NEGINF, l = 0.f;
        int yt = 0;
        for (; yt + 1 < tt; yt += 2) {
            const int y0 = 16*yt;
            const half4 ka0 = *(const half4*)&KT[(y0   +lmod)*20 + 4*ldiv];
            const half4 ka1 = *(const half4*)&KT[(y0+16+lmod)*20 + 4*ldiv];
            f32x4 s0 = __builtin_amdgcn_mfma_f32_16x16x16f16(
                ka0, qb, (f32x4){0.f,0.f,0.f,0.f}, 0, 0, 0);
            f32x4 s1 = __builtin_amdgcn_mfma_f32_16x16x16f16(
                ka1, qb, (f32x4){0.f,0.f,0.f,0.f}, 0, 0, 0);
            float mt = fmaxf(fmaxf(fmaxf(s0[0],s0[1]), fmaxf(s0[2],s0[3])),
                             fmaxf(fmaxf(s1[0],s1[1]), fmaxf(s1[2],s1[3])));
            mt = fmaxf(mt, __shfl_xor(mt, 16, 64));
            mt = fmaxf(mt, __shfl_xor(mt, 32, 64));
            const float mn = fmaxf(m, mt);
            const float alpha = EXP2F(m - mn);
            half4 pb0, pb1; float ps = 0.f;
            #pragma unroll
            for (int r = 0; r < 4; ++r) {
                const float p0 = EXP2F(s0[r] - mn);
                const float p1 = EXP2F(s1[r] - mn);
                pb0[r] = (half_t)p0; pb1[r] = (half_t)p1;
                ps += p0 + p1;
            }
            ps += __shfl_xor(ps, 16, 64);
            ps += __shfl_xor(ps, 32, 64);
            l = l*alpha + ps;  m = mn;
            o[0] *= alpha; o[1] *= alpha; o[2] *= alpha; o[3] *= alpha;
            const half4 fa0 = *(const half4*)&FOs[lmod*520 + y0      + 4*ldiv];
            const half4 fa1 = *(const half4*)&FOs[lmod*520 + y0 + 16 + 4*ldiv];
            o = __builtin_amdgcn_mfma_f32_16x16x16f16(fa0, pb0, o, 0, 0, 0);
            o = __builtin_amdgcn_mfma_f32_16x16x16f16(fa1, pb1, o, 0, 0, 0);
        }
        if (yt < tt) {
            const int y0 = 16*yt;
            const half4 ka0 = *(const half4*)&KT[(y0   +lmod)*20 + 4*ldiv];
            const half4 ka1 = *(const half4*)&KT[(y0+16+lmod)*20 + 4*ldiv];
            f32x4 s0 = __builtin_amdgcn_mfma_f32_16x16x16f16(
                ka0, qb, (f32x4){0.f,0.f,0.f,0.f}, 0, 0, 0);
            f32x4 s1 = __builtin_amdgcn_mfma_f32_16x16x16f16(
                ka1, qb, (f32x4){0.f,0.f,0.f,0.f}, 0, 0, 0);
            #pragma unroll
            for (int r = 0; r < 4; ++r)
                if (4*ldiv + r > lmod) s1[r] = NEGINF;
            float mt = fmaxf(fmaxf(fmaxf(s0[0],s0[1]), fmaxf(s0[2],s0[3])),
                             fmaxf(fmaxf(s1[0],s1[1]), fmaxf(s1[2],s1[3])));
            mt = fmaxf(mt, __shfl_xor(mt, 16, 64));
            mt = fmaxf(mt, __shfl_xor(mt, 32, 64));
            const float mn = fmaxf(m, mt);
            const float alpha = EXP2F(m - mn);
            half4 pb0, pb1; float ps = 0.f;
            #pragma unroll
            for (int r = 0; r < 4; ++r) {
                const float p0 = EXP2F(s0[r] - mn);
                const float p1 = EXP2F(s1[r] - mn);
                pb0[r] = (half_t)p0; pb1[r] = (half_t)p1;
                ps += p0 + p1;
            }
            ps += __shfl_xor(ps, 16, 64);
            ps += __shfl_xor(ps, 32, 64);
            l = l*alpha + ps;  m = mn;
            o[0] *= alpha; o[1] *= alpha; o[2] *= alpha; o[3] *= alpha;
            const half4 fa0 = *(const half4*)&FOs[lmod*520 + y0      + 4*ldiv];
            const half4 fa1 = *(const half4*)&FOs[lmod*520 + y0 + 16 + 4*ldiv];
            o = __builtin_amdgcn_mfma_f32_16x16x16f16(fa0, pb0, o, 0, 0, 0);
            o = __builtin_amdgcn_mfma_f32_16x16x16f16(fa1, pb1, o, 0, 0, 0);
        } else {
            const int y0 = 16*tt;
            const half4 ka = *(const half4*)&KT[(y0+lmod)*20 + 4*ldiv];
            f32x4 s = __builtin_amdgcn_mfma_f32_16x16x16f16(
                ka, qb, (f32x4){0.f,0.f,0.f,0.f}, 0, 0, 0);
            #pragma unroll
            for (int r = 0; r < 4; ++r)
                if (4*ldiv + r > lmod) s[r] = NEGINF;
            float mt = fmaxf(fmaxf(s[0],s[1]), fmaxf(s[2],s[3]));
            mt = fmaxf(mt, __shfl_xor(mt, 16, 64));
            mt = fmaxf(mt, __shfl_xor(mt, 32, 64));
            const float mn = fmaxf(m, mt);
            const float alpha = EXP2F(m - mn);
            half4 pb; float ps = 0.f;
            #pragma unroll
            for (int r = 0; r < 4; ++r) {
                const float p = EXP2F(s[r] - mn);
                pb[r] = (half_t)p; ps += p;
            }
            ps += __shfl_xor(ps, 16, 64);
            ps += __shfl_xor(ps, 32, 64);
            l = l*alpha + ps;  m = mn;
            o[0] *= alpha; o[1] *= alpha; o[2] *= alpha; o[3] *= alpha;
            const half4 fa4 = *(const half4*)&FOs[lmod*520 + y0 + 4*ldiv];
            o = __builtin_amdgcn_mfma_f32_16x16x16f16(fa4, pb, o, 0, 0, 0);
        }
        // ---- fused proj epilogue ----
        const float inv = 1.f/l;
        const int t = t0 + lmod;
        const bool tok = (t < TD);
        half4 tb;
        #pragma unroll
        for (int r = 0; r < 4; ++r)
            tb[r] = tok ? (half_t)(o[r]*inv) : (half_t)0.f;
        const long gbase = (long)(b*64)*FT + (long)f*TD + t;
        #pragma unroll
        for (int ot = 0; ot < 4; ++ot) {
            const half4 pf = *(const half4*)&PWh[(16*ot + lmod)*20 + 4*ldiv];
            f32x4 a2;
            #pragma unroll
            for (int r = 0; r < 4; ++r) a2[r] = PBl[16*ot + 4*ldiv + r];
            a2 = __builtin_amdgcn_mfma_f32_16x16x16f16(pf, tb, a2, 0, 0, 0);
            if (tok) {
                #pragma unroll
                for (int r = 0; r < 4; ++r) {
                    const int o64 = 16*ot + 4*ldiv + r;
                    float v = a2[r];
                    v = v >= 0.f ? v : app*v;
                    const long gi = gbase + (long)o64*FT;
                    out[gi] = v + x[gi];
                }
            }
        }
    }
}

extern "C" void kernel_launch(void* const* d_in, const int* in_sizes, int n_in,
                              void* d_out, int out_size, void* d_ws, size_t ws_size,
                              hipStream_t stream)
{
    const float* x     = (const float*)d_in[0];
    const float* fw    = (const float*)d_in[1];
    const float* fb_   = (const float*)d_in[2];
    const float* fg    = (const float*)d_in[3];
    const float* fbe   = (const float*)d_in[4];
    const float* fm    = (const float*)d_in[5];
    const float* fv_   = (const float*)d_in[6];
    const float* fa    = (const float*)d_in[7];
    const float* tw    = (const float*)d_in[8];
    const float* tb_   = (const float*)d_in[9];
    const float* tg    = (const float*)d_in[10];
    const float* tbe   = (const float*)d_in[11];
    const float* tm    = (const float*)d_in[12];
    const float* tv_   = (const float*)d_in[13];
    const float* ta    = (const float*)d_in[14];
    const float* pw    = (const float*)d_in[15];
    const float* pb_   = (const float*)d_in[16];
    const float* pg    = (const float*)d_in[17];
    const float* pbe   = (const float*)d_in[18];
    const float* pm    = (const float*)d_in[19];
    const float* pv_   = (const float*)d_in[20];
    const float* pa    = (const float*)d_in[21];
    float* out = (float*)d_out;

    // Workspace layout (bytes):
    //  A: fqh  f16 [2][48][FT]           24,672,000   (foTh f16 [2][16][TD][260]=8,320,000 aliases after T1)
    //  B: foh  f16 [2][16][FT]            8,224,000
    //  C: tqh  f16 [2][32][FT]           16,448,000
    //  D: fqTh f16 [96][FQT_PLANE]       24,960,000
    char* base = (char*)d_ws;
    const size_t szA = (size_t)BB*48*FT*sizeof(half_t);
    const size_t szB = (size_t)BB*16*FT*sizeof(half_t);
    const size_t szC = (size_t)BB*32*FT*sizeof(half_t);
    const size_t szD = (size_t)96*FQT_PLANE*sizeof(half_t);
    const size_t need = szA + szB + szC + szD;   // 74,304,000
    if (ws_size < need) return;
    half_t* fqh  = (half_t*)base;
    half_t* foTh = (half_t*)base;                // alias A (8.32 MB < szA)
    half_t* foh  = (half_t*)(base + szA);
    half_t* tqh  = (half_t*)(base + szA + szB);
    half_t* fqTh = (half_t*)(base + szA + szB + szC);

    stage1_kernel<<<dim3(BB*1004), dim3(256), 0, stream>>>(
        x, fw, fb_, fg, fbe, fm, fv_, fa, tw, tb_, tg, tbe, tm, tv_, ta, fqh, tqh);

    // T1: fq[b][c][f][t] -> fqT[b][c][t][f(pad 260)]
    transpose_h2h_kernel<<<dim3(BB*48, 5, 8), dim3(256), 0, stream>>>(
        fqh, fqTh, FD, TD, TD, FDP);

    fattn_kernel<<<dim3(BB*TD), dim3(512), 0, stream>>>(fqTh, foTh);

    // T2: foT[b][c][t][f(pad 260)] (f16) -> fo[b][c][f][t] (f16)
    transpose_h2h_kernel<<<dim3(BB*16, 8, 5), dim3(256), 0, stream>>>(
        foTh, foh, TD, FD, FDP, TD);

    const int tlds = (512*20 + 16*520 + 64*20)*(int)sizeof(half_t)
                   + 64*(int)sizeof(float);   // 39,936 B
    (void)hipFuncSetAttribute(reinterpret_cast<const void*>(tattn_kernel),
                        hipFuncAttributeMaxDynamicSharedMemorySize, tlds);
    tattn_kernel<<<dim3(BB*FD, 2), dim3(512), tlds, stream>>>(
        tqh, foh, pw, pb_, pg, pbe, pm, pv_, pa, x, out);
}